// Round 1
// baseline (601.072 us; speedup 1.0000x reference)
//
#include <hip/hip_runtime.h>
#include <hip/hip_bf16.h>
#include <stdint.h>

typedef __bf16 bf16x8 __attribute__((ext_vector_type(8)));
typedef float f32x4 __attribute__((ext_vector_type(4)));
typedef __hip_bfloat16 bf16;

__device__ __forceinline__ void gload16(const void* g, void* l) {
    __builtin_amdgcn_global_load_lds(
        (const __attribute__((address_space(1))) uint32_t*)g,
        (__attribute__((address_space(3))) uint32_t*)l,
        16, 0, 0);
}

// ---------------- elementwise convert fp32 -> bf16 (x) ----------------
__global__ void k_cvt_bf16(const float* __restrict__ in, bf16* __restrict__ out, int n4) {
    int i = blockIdx.x * blockDim.x + threadIdx.x;
    if (i >= n4) return;
    float4 v = reinterpret_cast<const float4*>(in)[i];
    union { bf16 h[4]; uint2 u; } pk;
    pk.h[0] = __float2bfloat16(v.x);
    pk.h[1] = __float2bfloat16(v.y);
    pk.h[2] = __float2bfloat16(v.z);
    pk.h[3] = __float2bfloat16(v.w);
    reinterpret_cast<uint2*>(out)[i] = pk.u;
}

// ---------------- rope cos/sin table [T][128] (cos j | sin j) ----------------
__global__ void k_rope_tbl(float* __restrict__ tbl) {
    int i = blockIdx.x * blockDim.x + threadIdx.x; // T*64
    int t = i >> 6, j = i & 63;
    float inv = powf(10000.0f, -(float)j * (1.0f / 64.0f));
    float f = (float)t * inv;
    tbl[t * 128 + j] = cosf(f);
    tbl[t * 128 + 64 + j] = sinf(f);
}

// ---------------- weight transpose + convert: W[k][n] fp32 -> Wt[n][k] bf16 ----------------
__global__ void k_wtrans(const float* __restrict__ w0, const float* __restrict__ w1,
                         const float* __restrict__ w2, const float* __restrict__ w3,
                         const float* __restrict__ w4, bf16* __restrict__ out) {
    __shared__ float tile[32][33];
    const float* srcs[5] = {w0, w1, w2, w3, w4};
    const float* src = srcs[blockIdx.z];
    bf16* dst = out + (size_t)blockIdx.z * 2048 * 2048;
    int k0 = blockIdx.x * 32, n0 = blockIdx.y * 32;
    int tx = threadIdx.x, ty = threadIdx.y; // 32 x 8
#pragma unroll
    for (int i = 0; i < 4; i++)
        tile[ty + 8 * i][tx] = src[(size_t)(k0 + ty + 8 * i) * 2048 + n0 + tx];
    __syncthreads();
#pragma unroll
    for (int i = 0; i < 4; i++)
        dst[(size_t)(n0 + ty + 8 * i) * 2048 + k0 + tx] = __float2bfloat16(tile[tx][ty + 8 * i]);
}

// ---------------- GEMM: C[z][M][N] = A[M][K] @ Bt[z][N][K]^T, bf16 in fp32 out ----------------
__global__ __launch_bounds__(256) void k_gemm(
    const bf16* __restrict__ A, const bf16* __restrict__ Bt, float* __restrict__ C,
    int M, int N, int K) {
    __shared__ __align__(16) bf16 As[128 * 64];
    __shared__ __align__(16) bf16 Bs[128 * 64];
    int lane = threadIdx.x & 63, wave = threadIdx.x >> 6;
    int g = lane >> 4, cc = lane & 15;
    int wr = wave >> 1, wc = wave & 1;
    size_t m0 = (size_t)blockIdx.x * 128, n0 = (size_t)blockIdx.y * 128;
    const bf16* Ab = A + m0 * K;
    const bf16* Bb = Bt + (size_t)blockIdx.z * N * K + n0 * K;
    float* Cb = C + (size_t)blockIdx.z * M * N + m0 * N + n0;

    f32x4 acc[4][4];
#pragma unroll
    for (int i = 0; i < 4; i++)
#pragma unroll
        for (int j = 0; j < 4; j++) acc[i][j] = {0.f, 0.f, 0.f, 0.f};

    int scol = (lane & 7) * 8;
    for (int k0 = 0; k0 < K; k0 += 64) {
#pragma unroll
        for (int i = 0; i < 4; i++) {
            int ch = wave * 4 + i;
            int row = ch * 8 + (lane >> 3);
            gload16(&Ab[(size_t)row * K + k0 + scol], &As[ch * 512]);
            gload16(&Bb[(size_t)row * K + k0 + scol], &Bs[ch * 512]);
        }
        __syncthreads();
#pragma unroll
        for (int kk = 0; kk < 2; kk++) {
            bf16x8 af[4], bfr[4];
#pragma unroll
            for (int m = 0; m < 4; m++)
                af[m] = *reinterpret_cast<const bf16x8*>(&As[(wr * 64 + m * 16 + cc) * 64 + kk * 32 + g * 8]);
#pragma unroll
            for (int n = 0; n < 4; n++)
                bfr[n] = *reinterpret_cast<const bf16x8*>(&Bs[(wc * 64 + n * 16 + cc) * 64 + kk * 32 + g * 8]);
#pragma unroll
            for (int m = 0; m < 4; m++)
#pragma unroll
                for (int n = 0; n < 4; n++)
                    acc[m][n] = __builtin_amdgcn_mfma_f32_16x16x32_bf16(af[m], bfr[n], acc[m][n], 0, 0, 0);
        }
        __syncthreads();
    }
#pragma unroll
    for (int m = 0; m < 4; m++)
#pragma unroll
        for (int n = 0; n < 4; n++)
#pragma unroll
            for (int r = 0; r < 4; r++) {
                size_t row = wr * 64 + m * 16 + g * 4 + r;
                Cb[row * N + (wc * 64 + n * 16 + cc)] = acc[m][n][r];
            }
}

// ---------------- RoPE + per-head RMS norm, fp32 [B*T][2048] -> bf16 [BH][T][128] ----------------
__global__ void k_rope_rms(const float* __restrict__ src, const float* __restrict__ rmsw,
                           const float* __restrict__ tbl, bf16* __restrict__ dst,
                           float outscale) {
    const int T = 2048;
    int wv = blockIdx.x * 4 + (threadIdx.x >> 6); // over B*T*H, h fastest
    int lane = threadIdx.x & 63;
    int h = wv & 15, bt = wv >> 4;
    int t = bt & (T - 1), b_ = bt >> 11;
    const float* p = src + (size_t)bt * 2048 + h * 128;
    float a = p[lane], b = p[lane + 64];
    float cs = tbl[t * 128 + lane], sn = tbl[t * 128 + 64 + lane];
    float r1 = a * cs - b * sn, r2 = a * sn + b * cs;
    float ss = r1 * r1 + r2 * r2;
#pragma unroll
    for (int d = 1; d < 64; d <<= 1) ss += __shfl_xor(ss, d, 64);
    float rs = rsqrtf(ss * (1.0f / 128.0f) + 1e-5f);
    size_t o = ((size_t)(b_ * 16 + h) * T + t) * 128;
    dst[o + lane] = __float2bfloat16(r1 * rs * rmsw[lane] * outscale);
    dst[o + lane + 64] = __float2bfloat16(r2 * rs * rmsw[lane + 64] * outscale);
}

// ---------------- V transpose: fp32 [B*T][2048] -> bf16 Vt [BH][128][T] ----------------
__global__ void k_vtrans(const float* __restrict__ V, bf16* __restrict__ Vt) {
    const int T = 2048;
    __shared__ float tile[32][33];
    int bh = blockIdx.z, b_ = bh >> 4, h = bh & 15;
    int t0 = blockIdx.x * 32, d0 = blockIdx.y * 32;
    int tx = threadIdx.x, ty = threadIdx.y; // 32 x 8
#pragma unroll
    for (int i = 0; i < 4; i++)
        tile[ty + 8 * i][tx] = V[((size_t)(b_ * T + t0 + ty + 8 * i)) * 2048 + h * 128 + d0 + tx];
    __syncthreads();
#pragma unroll
    for (int i = 0; i < 4; i++)
        Vt[((size_t)bh * 128 + d0 + ty + 8 * i) * T + t0 + tx] = __float2bfloat16(tile[tx][ty + 8 * i]);
}

// ---------------- causal flash attention: Q,K [BH][T][128], Vt [BH][128][T] -> Y fp32 [BH][T][128] ----------------
__global__ __launch_bounds__(256) void k_attn(
    const bf16* __restrict__ Q, const bf16* __restrict__ K,
    const bf16* __restrict__ Vt, float* __restrict__ Y) {
    const int T = 2048;
    __shared__ __align__(16) bf16 Ks[64 * 128];
    __shared__ __align__(16) bf16 Vs[128 * 64];
    __shared__ __align__(16) bf16 Ps[64 * 72];
    int lane = threadIdx.x & 63, wave = threadIdx.x >> 6;
    int g = lane >> 4, c = lane & 15;
    int bh = blockIdx.y;
    int q0 = blockIdx.x * 64;
    const bf16* Qb = Q + (size_t)bh * T * 128;
    const bf16* Kb = K + (size_t)bh * T * 128;
    const bf16* Vb = Vt + (size_t)bh * 128 * T;

    bf16x8 qf[4];
    {
        int qrow = q0 + wave * 16 + c;
#pragma unroll
        for (int kk = 0; kk < 4; kk++)
            qf[kk] = *reinterpret_cast<const bf16x8*>(&Qb[(size_t)qrow * 128 + kk * 32 + g * 8]);
    }
    f32x4 acc[8];
#pragma unroll
    for (int i = 0; i < 8; i++) acc[i] = {0.f, 0.f, 0.f, 0.f};
    float mrow[4] = {-INFINITY, -INFINITY, -INFINITY, -INFINITY};
    float lrow[4] = {0.f, 0.f, 0.f, 0.f};

    int ntiles = blockIdx.x + 1;
    for (int it = 0; it < ntiles; ++it) {
        int kv0 = it * 64;
#pragma unroll
        for (int i = 0; i < 4; i++) {
            int ch = wave * 4 + i;
            gload16(&Kb[(size_t)(kv0 + ch * 4 + (lane >> 4)) * 128 + (lane & 15) * 8], &Ks[ch * 512]);
        }
#pragma unroll
        for (int i = 0; i < 4; i++) {
            int ch = wave * 4 + i;
            gload16(&Vb[(size_t)(ch * 8 + (lane >> 3)) * T + kv0 + (lane & 7) * 8], &Vs[ch * 512]);
        }
        __syncthreads();

        f32x4 s[4];
#pragma unroll
        for (int nf = 0; nf < 4; nf++) s[nf] = {0.f, 0.f, 0.f, 0.f};
#pragma unroll
        for (int kk = 0; kk < 4; kk++)
#pragma unroll
            for (int nf = 0; nf < 4; nf++) {
                bf16x8 kf = *reinterpret_cast<const bf16x8*>(&Ks[(nf * 16 + c) * 128 + kk * 32 + g * 8]);
                s[nf] = __builtin_amdgcn_mfma_f32_16x16x32_bf16(qf[kk], kf, s[nf], 0, 0, 0);
            }
        if (it == ntiles - 1) {
#pragma unroll
            for (int nf = 0; nf < 4; nf++)
#pragma unroll
                for (int r = 0; r < 4; r++)
                    if (nf * 16 + c > wave * 16 + 4 * g + r) s[nf][r] = -1e30f;
        }
#pragma unroll
        for (int r = 0; r < 4; r++) {
            float mx = fmaxf(fmaxf(s[0][r], s[1][r]), fmaxf(s[2][r], s[3][r]));
#pragma unroll
            for (int d = 1; d < 16; d <<= 1) mx = fmaxf(mx, __shfl_xor(mx, d, 64));
            float mnew = fmaxf(mrow[r], mx);
            float alpha = __expf(mrow[r] - mnew);
            mrow[r] = mnew;
            float rsum = 0.f;
#pragma unroll
            for (int nf = 0; nf < 4; nf++) {
                float p = __expf(s[nf][r] - mnew);
                s[nf][r] = p;
                rsum += p;
            }
#pragma unroll
            for (int d = 1; d < 16; d <<= 1) rsum += __shfl_xor(rsum, d, 64);
            lrow[r] = lrow[r] * alpha + rsum;
#pragma unroll
            for (int nf = 0; nf < 8; nf++) acc[nf][r] *= alpha;
        }
#pragma unroll
        for (int nf = 0; nf < 4; nf++)
#pragma unroll
            for (int r = 0; r < 4; r++)
                Ps[(wave * 16 + 4 * g + r) * 72 + nf * 16 + c] = __float2bfloat16(s[nf][r]);
        // PV (P rows are wave-private; LDS write->read ordered by lgkmcnt within wave)
#pragma unroll
        for (int kk2 = 0; kk2 < 2; kk2++) {
            bf16x8 pf = *reinterpret_cast<const bf16x8*>(&Ps[(wave * 16 + c) * 72 + kk2 * 32 + g * 8]);
#pragma unroll
            for (int nf = 0; nf < 8; nf++) {
                bf16x8 vf = *reinterpret_cast<const bf16x8*>(&Vs[(nf * 16 + c) * 64 + kk2 * 32 + g * 8]);
                acc[nf] = __builtin_amdgcn_mfma_f32_16x16x32_bf16(pf, vf, acc[nf], 0, 0, 0);
            }
        }
        __syncthreads();
    }
#pragma unroll
    for (int r = 0; r < 4; r++) {
        float inv = 1.0f / lrow[r];
        size_t row = q0 + wave * 16 + 4 * g + r;
#pragma unroll
        for (int nf = 0; nf < 8; nf++)
            Y[(size_t)bh * T * 128 + row * 128 + nf * 16 + c] = acc[nf][r] * inv;
    }
}

// ---------------- o-norm + silu(gate) gating -> bf16 [B*T][2048] ----------------
__global__ void k_finalize(const float* __restrict__ Y, const float* __restrict__ gate,
                           const float* __restrict__ ow, bf16* __restrict__ out) {
    const int T = 2048;
    int wv = blockIdx.x * 4 + (threadIdx.x >> 6); // over BH*T
    int lane = threadIdx.x & 63;
    int t = wv & (T - 1), bh = wv >> 11;
    int b_ = bh >> 4, h = bh & 15;
    const float* y = Y + (size_t)wv * 128;
    float y1 = y[lane], y2 = y[lane + 64];
    float ss = y1 * y1 + y2 * y2;
#pragma unroll
    for (int d = 1; d < 64; d <<= 1) ss += __shfl_xor(ss, d, 64);
    float rs = rsqrtf(ss * (1.0f / 128.0f) + 1e-5f);
    size_t gi = ((size_t)(b_ * T + t)) * 2048 + h * 128;
    float g1 = gate[gi + lane], g2 = gate[gi + lane + 64];
    g1 = g1 / (1.f + __expf(-g1));
    g2 = g2 / (1.f + __expf(-g2));
    out[gi + lane] = __float2bfloat16(y1 * rs * ow[lane] * g1);
    out[gi + lane + 64] = __float2bfloat16(y2 * rs * ow[lane + 64] * g2);
}

extern "C" void kernel_launch(void* const* d_in, const int* in_sizes, int n_in,
                              void* d_out, int out_size, void* d_ws, size_t ws_size,
                              hipStream_t stream) {
    const float* x  = (const float*)d_in[0];
    const float* Wq = (const float*)d_in[1];
    const float* Wk = (const float*)d_in[2];
    const float* Wv = (const float*)d_in[3];
    const float* Wg = (const float*)d_in[4];
    const float* Wo = (const float*)d_in[5];
    const float* qw = (const float*)d_in[6];
    const float* kw = (const float*)d_in[7];
    const float* ow = (const float*)d_in[8];

    const size_t M = 4096, HID = 2048;
    char* w = (char*)d_ws;
    bf16*  xb    = (bf16*)(w);                     // 16,777,216 B
    bf16*  Wt    = (bf16*)(w + 16777216);          // 41,943,040 B  [5][2048][2048]
    float* qkvg  = (float*)(w + 58720256);         // 134,217,728 B [4][4096][2048]
    bf16*  q_att = (bf16*)(w + 192937984);         // 16,777,216 B  [32][2048][128]
    bf16*  k_att = (bf16*)(w + 209715200);         // 16,777,216 B
    bf16*  vt    = (bf16*)(w + 226492416);         // 16,777,216 B  [32][128][2048]
    float* tbl   = (float*)(w + 243269632);        // 1,048,576 B   [2048][128]
    float* y_att = qkvg;                           // reuse q slot (dead after rope)
    bf16*  yg    = (bf16*)(qkvg + M * HID);        // reuse k slot (dead after rope)

    k_cvt_bf16<<<8192, 256, 0, stream>>>(x, xb, (int)(M * HID / 4));
    k_rope_tbl<<<512, 256, 0, stream>>>(tbl);
    k_wtrans<<<dim3(64, 64, 5), dim3(32, 8), 0, stream>>>(Wq, Wk, Wv, Wg, Wo, Wt);
    // fused Q/K/V/Gate projection
    k_gemm<<<dim3(32, 16, 4), 256, 0, stream>>>(xb, Wt, qkvg, (int)M, 2048, 2048);
    // rope + rms (+ fold 1/sqrt(D) into q)
    k_rope_rms<<<16384, 256, 0, stream>>>(qkvg, qw, tbl, q_att, 0.08838834764831845f);
    k_rope_rms<<<16384, 256, 0, stream>>>(qkvg + M * HID, kw, tbl, k_att, 1.0f);
    k_vtrans<<<dim3(64, 4, 32), dim3(32, 8), 0, stream>>>(qkvg + 2 * M * HID, vt);
    k_attn<<<dim3(32, 32), 256, 0, stream>>>(q_att, k_att, vt, y_att);
    k_finalize<<<16384, 256, 0, stream>>>(y_att, qkvg + 3 * M * HID, ow, yg);
    // output projection
    k_gemm<<<dim3(32, 16, 1), 256, 0, stream>>>(yg, Wt + (size_t)4 * 2048 * 2048, (float*)d_out,
                                                (int)M, 2048, 2048);
}

// Round 2
// 594.981 us; speedup vs baseline: 1.0102x; 1.0102x over previous
//
#include <hip/hip_runtime.h>
#include <hip/hip_bf16.h>
#include <stdint.h>

typedef __bf16 bf16x8 __attribute__((ext_vector_type(8)));
typedef float f32x4 __attribute__((ext_vector_type(4)));
typedef __hip_bfloat16 bf16;

__device__ __forceinline__ void gload16(const void* g, void* l) {
    __builtin_amdgcn_global_load_lds(
        (const __attribute__((address_space(1))) uint32_t*)g,
        (__attribute__((address_space(3))) uint32_t*)l,
        16, 0, 0);
}

// ---------------- elementwise convert fp32 -> bf16 (x) ----------------
__global__ void k_cvt_bf16(const float* __restrict__ in, bf16* __restrict__ out, int n4) {
    int i = blockIdx.x * blockDim.x + threadIdx.x;
    if (i >= n4) return;
    float4 v = reinterpret_cast<const float4*>(in)[i];
    union { bf16 h[4]; uint2 u; } pk;
    pk.h[0] = __float2bfloat16(v.x);
    pk.h[1] = __float2bfloat16(v.y);
    pk.h[2] = __float2bfloat16(v.z);
    pk.h[3] = __float2bfloat16(v.w);
    reinterpret_cast<uint2*>(out)[i] = pk.u;
}

// ---------------- rope cos/sin table [T][128] (cos j | sin j) ----------------
__global__ void k_rope_tbl(float* __restrict__ tbl) {
    int i = blockIdx.x * blockDim.x + threadIdx.x; // T*64
    int t = i >> 6, j = i & 63;
    float inv = powf(10000.0f, -(float)j * (1.0f / 64.0f));
    float f = (float)t * inv;
    tbl[t * 128 + j] = cosf(f);
    tbl[t * 128 + 64 + j] = sinf(f);
}

// ---------------- weight transpose + convert: W[k][n] fp32 -> Wt[n][k] bf16 ----------------
__global__ void k_wtrans(const float* __restrict__ w0, const float* __restrict__ w1,
                         const float* __restrict__ w2, const float* __restrict__ w3,
                         const float* __restrict__ w4, bf16* __restrict__ out) {
    __shared__ float tile[32][33];
    const float* srcs[5] = {w0, w1, w2, w3, w4};
    const float* src = srcs[blockIdx.z];
    bf16* dst = out + (size_t)blockIdx.z * 2048 * 2048;
    int k0 = blockIdx.x * 32, n0 = blockIdx.y * 32;
    int tx = threadIdx.x, ty = threadIdx.y; // 32 x 8
#pragma unroll
    for (int i = 0; i < 4; i++)
        tile[ty + 8 * i][tx] = src[(size_t)(k0 + ty + 8 * i) * 2048 + n0 + tx];
    __syncthreads();
#pragma unroll
    for (int i = 0; i < 4; i++)
        dst[(size_t)(n0 + ty + 8 * i) * 2048 + k0 + tx] = __float2bfloat16(tile[tx][ty + 8 * i]);
}

// ---------------- GEMM: C[z][M][N] = A[M][K] @ Bt[z][N][K]^T, bf16 in fp32 out ----------------
__global__ __launch_bounds__(256) void k_gemm(
    const bf16* __restrict__ A, const bf16* __restrict__ Bt, float* __restrict__ C,
    int M, int N, int K) {
    __shared__ __align__(16) bf16 As[128 * 64];
    __shared__ __align__(16) bf16 Bs[128 * 64];
    int lane = threadIdx.x & 63, wave = threadIdx.x >> 6;
    int g = lane >> 4, cc = lane & 15;
    int wr = wave >> 1, wc = wave & 1;
    size_t m0 = (size_t)blockIdx.x * 128, n0 = (size_t)blockIdx.y * 128;
    const bf16* Ab = A + m0 * K;
    const bf16* Bb = Bt + (size_t)blockIdx.z * N * K + n0 * K;
    float* Cb = C + (size_t)blockIdx.z * M * N + m0 * N + n0;

    f32x4 acc[4][4];
#pragma unroll
    for (int i = 0; i < 4; i++)
#pragma unroll
        for (int j = 0; j < 4; j++) acc[i][j] = {0.f, 0.f, 0.f, 0.f};

    int scol = (lane & 7) * 8;
    for (int k0 = 0; k0 < K; k0 += 64) {
#pragma unroll
        for (int i = 0; i < 4; i++) {
            int ch = wave * 4 + i;
            int row = ch * 8 + (lane >> 3);
            gload16(&Ab[(size_t)row * K + k0 + scol], &As[ch * 512]);
            gload16(&Bb[(size_t)row * K + k0 + scol], &Bs[ch * 512]);
        }
        __syncthreads();
#pragma unroll
        for (int kk = 0; kk < 2; kk++) {
            bf16x8 af[4], bfr[4];
#pragma unroll
            for (int m = 0; m < 4; m++)
                af[m] = *reinterpret_cast<const bf16x8*>(&As[(wr * 64 + m * 16 + cc) * 64 + kk * 32 + g * 8]);
#pragma unroll
            for (int n = 0; n < 4; n++)
                bfr[n] = *reinterpret_cast<const bf16x8*>(&Bs[(wc * 64 + n * 16 + cc) * 64 + kk * 32 + g * 8]);
#pragma unroll
            for (int m = 0; m < 4; m++)
#pragma unroll
                for (int n = 0; n < 4; n++)
                    acc[m][n] = __builtin_amdgcn_mfma_f32_16x16x32_bf16(af[m], bfr[n], acc[m][n], 0, 0, 0);
        }
        __syncthreads();
    }
#pragma unroll
    for (int m = 0; m < 4; m++)
#pragma unroll
        for (int n = 0; n < 4; n++)
#pragma unroll
            for (int r = 0; r < 4; r++) {
                size_t row = wr * 64 + m * 16 + g * 4 + r;
                Cb[row * N + (wc * 64 + n * 16 + cc)] = acc[m][n][r];
            }
}

// ---------------- RoPE + per-head RMS norm, fp32 [B*T][2048] -> bf16 [BH][T][128] ----------------
__global__ void k_rope_rms(const float* __restrict__ src, const float* __restrict__ rmsw,
                           const float* __restrict__ tbl, bf16* __restrict__ dst,
                           float outscale) {
    const int T = 2048;
    int wv = blockIdx.x * 4 + (threadIdx.x >> 6); // over B*T*H, h fastest
    int lane = threadIdx.x & 63;
    int h = wv & 15, bt = wv >> 4;
    int t = bt & (T - 1), b_ = bt >> 11;
    const float* p = src + (size_t)bt * 2048 + h * 128;
    float a = p[lane], b = p[lane + 64];
    float cs = tbl[t * 128 + lane], sn = tbl[t * 128 + 64 + lane];
    float r1 = a * cs - b * sn, r2 = a * sn + b * cs;
    float ss = r1 * r1 + r2 * r2;
#pragma unroll
    for (int d = 1; d < 64; d <<= 1) ss += __shfl_xor(ss, d, 64);
    float rs = rsqrtf(ss * (1.0f / 128.0f) + 1e-5f);
    size_t o = ((size_t)(b_ * 16 + h) * T + t) * 128;
    dst[o + lane] = __float2bfloat16(r1 * rs * rmsw[lane] * outscale);
    dst[o + lane + 64] = __float2bfloat16(r2 * rs * rmsw[lane + 64] * outscale);
}

// ---------------- V transpose: fp32 [B*T][2048] -> bf16 Vt [BH][128][T] ----------------
__global__ void k_vtrans(const float* __restrict__ V, bf16* __restrict__ Vt) {
    const int T = 2048;
    __shared__ float tile[32][33];
    int bh = blockIdx.z, b_ = bh >> 4, h = bh & 15;
    int t0 = blockIdx.x * 32, d0 = blockIdx.y * 32;
    int tx = threadIdx.x, ty = threadIdx.y; // 32 x 8
#pragma unroll
    for (int i = 0; i < 4; i++)
        tile[ty + 8 * i][tx] = V[((size_t)(b_ * T + t0 + ty + 8 * i)) * 2048 + h * 128 + d0 + tx];
    __syncthreads();
#pragma unroll
    for (int i = 0; i < 4; i++)
        Vt[((size_t)bh * 128 + d0 + ty + 8 * i) * T + t0 + tx] = __float2bfloat16(tile[tx][ty + 8 * i]);
}

// ---------------- causal flash attention: Q,K [BH][T][128], Vt [BH][128][T] -> Y fp32 [BH][T][128]
// v2: no K/V LDS staging (K/V are L2-resident: 4 heads/XCD = 4MB = L2). No barriers at all.
// Heavy-first causal scheduling + XCD-grouped heads: wg = qt'*32+bh, XCD=wg%8=bh%8.
__global__ __launch_bounds__(256) void k_attn(
    const bf16* __restrict__ Q, const bf16* __restrict__ K,
    const bf16* __restrict__ Vt, float* __restrict__ Y) {
    const int T = 2048;
    __shared__ __align__(16) bf16 Ps[64 * 72];
    int lane = threadIdx.x & 63, wave = threadIdx.x >> 6;
    int g = lane >> 4, c = lane & 15;
    int wg = blockIdx.x;
    int bh = wg & 31;          // XCD = wg%8 = bh%8 -> 4 heads per XCD (K+V = 4MB = one L2)
    int qt = 31 - (wg >> 5);   // heavy q-tiles launch first
    int q0 = qt * 64;
    const bf16* Qb = Q + (size_t)bh * T * 128;
    const bf16* Kb = K + (size_t)bh * T * 128;
    const bf16* Vb = Vt + (size_t)bh * 128 * T;

    bf16x8 qf[4];
    {
        int qrow = q0 + wave * 16 + c;
#pragma unroll
        for (int kk = 0; kk < 4; kk++)
            qf[kk] = *reinterpret_cast<const bf16x8*>(&Qb[(size_t)qrow * 128 + kk * 32 + g * 8]);
    }
    f32x4 acc[8];
#pragma unroll
    for (int i = 0; i < 8; i++) acc[i] = {0.f, 0.f, 0.f, 0.f};
    float mrow[4] = {-INFINITY, -INFINITY, -INFINITY, -INFINITY};
    float lrow[4] = {0.f, 0.f, 0.f, 0.f};

    int ntiles = qt + 1;
    for (int it = 0; it < ntiles; ++it) {
        int kv0 = it * 64;
        // ---- QK^T: K fragments straight from global (L2-hit) ----
        f32x4 s[4];
#pragma unroll
        for (int nf = 0; nf < 4; nf++) s[nf] = {0.f, 0.f, 0.f, 0.f};
#pragma unroll
        for (int nf = 0; nf < 4; nf++) {
            bf16x8 kf[4];
#pragma unroll
            for (int kk = 0; kk < 4; kk++)
                kf[kk] = *reinterpret_cast<const bf16x8*>(
                    &Kb[(size_t)(kv0 + nf * 16 + c) * 128 + kk * 32 + g * 8]);
#pragma unroll
            for (int kk = 0; kk < 4; kk++)
                s[nf] = __builtin_amdgcn_mfma_f32_16x16x32_bf16(qf[kk], kf[kk], s[nf], 0, 0, 0);
        }
        if (it == ntiles - 1) {
#pragma unroll
            for (int nf = 0; nf < 4; nf++)
#pragma unroll
                for (int r = 0; r < 4; r++)
                    if (nf * 16 + c > wave * 16 + 4 * g + r) s[nf][r] = -1e30f;
        }
        // ---- online softmax (16-lane row groups) ----
#pragma unroll
        for (int r = 0; r < 4; r++) {
            float mx = fmaxf(fmaxf(s[0][r], s[1][r]), fmaxf(s[2][r], s[3][r]));
#pragma unroll
            for (int d = 1; d < 16; d <<= 1) mx = fmaxf(mx, __shfl_xor(mx, d, 64));
            float mnew = fmaxf(mrow[r], mx);
            float alpha = __expf(mrow[r] - mnew);
            mrow[r] = mnew;
            float rsum = 0.f;
#pragma unroll
            for (int nf = 0; nf < 4; nf++) {
                float p = __expf(s[nf][r] - mnew);
                s[nf][r] = p;
                rsum += p;
            }
#pragma unroll
            for (int d = 1; d < 16; d <<= 1) rsum += __shfl_xor(rsum, d, 64);
            lrow[r] = lrow[r] * alpha + rsum;
#pragma unroll
            for (int nf = 0; nf < 8; nf++) acc[nf][r] *= alpha;
        }
        // ---- P -> LDS (wave-private rows; lgkmcnt orders write->read, no barrier) ----
#pragma unroll
        for (int nf = 0; nf < 4; nf++)
#pragma unroll
            for (int r = 0; r < 4; r++)
                Ps[(wave * 16 + 4 * g + r) * 72 + nf * 16 + c] = __float2bfloat16(s[nf][r]);
        // ---- PV: V^T fragments straight from global (L2-hit) ----
#pragma unroll
        for (int kk2 = 0; kk2 < 2; kk2++) {
            bf16x8 pf = *reinterpret_cast<const bf16x8*>(&Ps[(wave * 16 + c) * 72 + kk2 * 32 + g * 8]);
#pragma unroll
            for (int nf = 0; nf < 8; nf++) {
                bf16x8 vf = *reinterpret_cast<const bf16x8*>(
                    &Vb[(size_t)(nf * 16 + c) * T + kv0 + kk2 * 32 + g * 8]);
                acc[nf] = __builtin_amdgcn_mfma_f32_16x16x32_bf16(pf, vf, acc[nf], 0, 0, 0);
            }
        }
    }
#pragma unroll
    for (int r = 0; r < 4; r++) {
        float inv = 1.0f / lrow[r];
        size_t row = q0 + wave * 16 + 4 * g + r;
#pragma unroll
        for (int nf = 0; nf < 8; nf++)
            Y[(size_t)bh * T * 128 + row * 128 + nf * 16 + c] = acc[nf][r] * inv;
    }
}

// ---------------- o-norm + silu(gate) gating -> bf16 [B*T][2048] ----------------
__global__ void k_finalize(const float* __restrict__ Y, const float* __restrict__ gate,
                           const float* __restrict__ ow, bf16* __restrict__ out) {
    const int T = 2048;
    int wv = blockIdx.x * 4 + (threadIdx.x >> 6); // over BH*T
    int lane = threadIdx.x & 63;
    int t = wv & (T - 1), bh = wv >> 11;
    int b_ = bh >> 4, h = bh & 15;
    const float* y = Y + (size_t)wv * 128;
    float y1 = y[lane], y2 = y[lane + 64];
    float ss = y1 * y1 + y2 * y2;
#pragma unroll
    for (int d = 1; d < 64; d <<= 1) ss += __shfl_xor(ss, d, 64);
    float rs = rsqrtf(ss * (1.0f / 128.0f) + 1e-5f);
    size_t gi = ((size_t)(b_ * T + t)) * 2048 + h * 128;
    float g1 = gate[gi + lane], g2 = gate[gi + lane + 64];
    g1 = g1 / (1.f + __expf(-g1));
    g2 = g2 / (1.f + __expf(-g2));
    out[gi + lane] = __float2bfloat16(y1 * rs * ow[lane] * g1);
    out[gi + lane + 64] = __float2bfloat16(y2 * rs * ow[lane + 64] * g2);
}

extern "C" void kernel_launch(void* const* d_in, const int* in_sizes, int n_in,
                              void* d_out, int out_size, void* d_ws, size_t ws_size,
                              hipStream_t stream) {
    const float* x  = (const float*)d_in[0];
    const float* Wq = (const float*)d_in[1];
    const float* Wk = (const float*)d_in[2];
    const float* Wv = (const float*)d_in[3];
    const float* Wg = (const float*)d_in[4];
    const float* Wo = (const float*)d_in[5];
    const float* qw = (const float*)d_in[6];
    const float* kw = (const float*)d_in[7];
    const float* ow = (const float*)d_in[8];

    const size_t M = 4096, HID = 2048;
    char* w = (char*)d_ws;
    bf16*  xb    = (bf16*)(w);                     // 16,777,216 B
    bf16*  Wt    = (bf16*)(w + 16777216);          // 41,943,040 B  [5][2048][2048]
    float* qkvg  = (float*)(w + 58720256);         // 134,217,728 B [4][4096][2048]
    bf16*  q_att = (bf16*)(w + 192937984);         // 16,777,216 B  [32][2048][128]
    bf16*  k_att = (bf16*)(w + 209715200);         // 16,777,216 B
    bf16*  vt    = (bf16*)(w + 226492416);         // 16,777,216 B  [32][128][2048]
    float* tbl   = (float*)(w + 243269632);        // 1,048,576 B   [2048][128]
    float* y_att = qkvg;                           // reuse q slot (dead after rope)
    bf16*  yg    = (bf16*)(qkvg + M * HID);        // reuse k slot (dead after rope)

    k_cvt_bf16<<<8192, 256, 0, stream>>>(x, xb, (int)(M * HID / 4));
    k_rope_tbl<<<512, 256, 0, stream>>>(tbl);
    k_wtrans<<<dim3(64, 64, 5), dim3(32, 8), 0, stream>>>(Wq, Wk, Wv, Wg, Wo, Wt);
    // fused Q/K/V/Gate projection
    k_gemm<<<dim3(32, 16, 4), 256, 0, stream>>>(xb, Wt, qkvg, (int)M, 2048, 2048);
    // rope + rms (+ fold 1/sqrt(D) into q)
    k_rope_rms<<<16384, 256, 0, stream>>>(qkvg, qw, tbl, q_att, 0.08838834764831845f);
    k_rope_rms<<<16384, 256, 0, stream>>>(qkvg + M * HID, kw, tbl, k_att, 1.0f);
    k_vtrans<<<dim3(64, 4, 32), dim3(32, 8), 0, stream>>>(qkvg + 2 * M * HID, vt);
    k_attn<<<1024, 256, 0, stream>>>(q_att, k_att, vt, y_att);
    k_finalize<<<16384, 256, 0, stream>>>(y_att, qkvg + 3 * M * HID, ow, yg);
    // output projection
    k_gemm<<<dim3(32, 16, 1), 256, 0, stream>>>(yg, Wt + (size_t)4 * 2048 * 2048, (float*)d_out,
                                                (int)M, 2048, 2048);
}

// Round 3
// 399.261 us; speedup vs baseline: 1.5055x; 1.4902x over previous
//
#include <hip/hip_runtime.h>
#include <hip/hip_bf16.h>
#include <stdint.h>

typedef __bf16 bf16x8 __attribute__((ext_vector_type(8)));
typedef float f32x4 __attribute__((ext_vector_type(4)));
typedef __hip_bfloat16 bf16;

__device__ __forceinline__ void gload16(const void* g, void* l) {
    __builtin_amdgcn_global_load_lds(
        (const __attribute__((address_space(1))) uint32_t*)g,
        (__attribute__((address_space(3))) uint32_t*)l,
        16, 0, 0);
}

// ---------------- elementwise convert fp32 -> bf16 (x) ----------------
__global__ void k_cvt_bf16(const float* __restrict__ in, bf16* __restrict__ out, int n4) {
    int i = blockIdx.x * blockDim.x + threadIdx.x;
    if (i >= n4) return;
    float4 v = reinterpret_cast<const float4*>(in)[i];
    union { bf16 h[4]; uint2 u; } pk;
    pk.h[0] = __float2bfloat16(v.x);
    pk.h[1] = __float2bfloat16(v.y);
    pk.h[2] = __float2bfloat16(v.z);
    pk.h[3] = __float2bfloat16(v.w);
    reinterpret_cast<uint2*>(out)[i] = pk.u;
}

// ---------------- rope cos/sin table [T][128] (cos j | sin j) ----------------
__global__ void k_rope_tbl(float* __restrict__ tbl) {
    int i = blockIdx.x * blockDim.x + threadIdx.x; // T*64
    int t = i >> 6, j = i & 63;
    float inv = powf(10000.0f, -(float)j * (1.0f / 64.0f));
    float f = (float)t * inv;
    tbl[t * 128 + j] = cosf(f);
    tbl[t * 128 + 64 + j] = sinf(f);
}

// ---------------- weight transpose + convert: W[k][n] fp32 -> Wt[n][k] bf16 ----------------
__global__ void k_wtrans(const float* __restrict__ w0, const float* __restrict__ w1,
                         const float* __restrict__ w2, const float* __restrict__ w3,
                         const float* __restrict__ w4, bf16* __restrict__ out) {
    __shared__ float tile[32][33];
    const float* srcs[5] = {w0, w1, w2, w3, w4};
    const float* src = srcs[blockIdx.z];
    bf16* dst = out + (size_t)blockIdx.z * 2048 * 2048;
    int k0 = blockIdx.x * 32, n0 = blockIdx.y * 32;
    int tx = threadIdx.x, ty = threadIdx.y; // 32 x 8
#pragma unroll
    for (int i = 0; i < 4; i++)
        tile[ty + 8 * i][tx] = src[(size_t)(k0 + ty + 8 * i) * 2048 + n0 + tx];
    __syncthreads();
#pragma unroll
    for (int i = 0; i < 4; i++)
        dst[(size_t)(n0 + ty + 8 * i) * 2048 + k0 + tx] = __float2bfloat16(tile[tx][ty + 8 * i]);
}

// ---------------- GEMM: C[z][M][N] = A[M][K] @ Bt[z][N][K]^T, bf16 in fp32 out ----------------
__global__ __launch_bounds__(256) void k_gemm(
    const bf16* __restrict__ A, const bf16* __restrict__ Bt, float* __restrict__ C,
    int M, int N, int K) {
    __shared__ __align__(16) bf16 As[128 * 64];
    __shared__ __align__(16) bf16 Bs[128 * 64];
    int lane = threadIdx.x & 63, wave = threadIdx.x >> 6;
    int g = lane >> 4, cc = lane & 15;
    int wr = wave >> 1, wc = wave & 1;
    size_t m0 = (size_t)blockIdx.x * 128, n0 = (size_t)blockIdx.y * 128;
    const bf16* Ab = A + m0 * K;
    const bf16* Bb = Bt + (size_t)blockIdx.z * N * K + n0 * K;
    float* Cb = C + (size_t)blockIdx.z * M * N + m0 * N + n0;

    f32x4 acc[4][4];
#pragma unroll
    for (int i = 0; i < 4; i++)
#pragma unroll
        for (int j = 0; j < 4; j++) acc[i][j] = {0.f, 0.f, 0.f, 0.f};

    int scol = (lane & 7) * 8;
    for (int k0 = 0; k0 < K; k0 += 64) {
#pragma unroll
        for (int i = 0; i < 4; i++) {
            int ch = wave * 4 + i;
            int row = ch * 8 + (lane >> 3);
            gload16(&Ab[(size_t)row * K + k0 + scol], &As[ch * 512]);
            gload16(&Bb[(size_t)row * K + k0 + scol], &Bs[ch * 512]);
        }
        __syncthreads();
#pragma unroll
        for (int kk = 0; kk < 2; kk++) {
            bf16x8 af[4], bfr[4];
#pragma unroll
            for (int m = 0; m < 4; m++)
                af[m] = *reinterpret_cast<const bf16x8*>(&As[(wr * 64 + m * 16 + cc) * 64 + kk * 32 + g * 8]);
#pragma unroll
            for (int n = 0; n < 4; n++)
                bfr[n] = *reinterpret_cast<const bf16x8*>(&Bs[(wc * 64 + n * 16 + cc) * 64 + kk * 32 + g * 8]);
#pragma unroll
            for (int m = 0; m < 4; m++)
#pragma unroll
                for (int n = 0; n < 4; n++)
                    acc[m][n] = __builtin_amdgcn_mfma_f32_16x16x32_bf16(af[m], bfr[n], acc[m][n], 0, 0, 0);
        }
        __syncthreads();
    }
#pragma unroll
    for (int m = 0; m < 4; m++)
#pragma unroll
        for (int n = 0; n < 4; n++)
#pragma unroll
            for (int r = 0; r < 4; r++) {
                size_t row = wr * 64 + m * 16 + g * 4 + r;
                Cb[row * N + (wc * 64 + n * 16 + cc)] = acc[m][n][r];
            }
}

// ---------------- RoPE + per-head RMS norm, fp32 [B*T][2048] -> bf16 [BH][T][128] ----------------
__global__ void k_rope_rms(const float* __restrict__ src, const float* __restrict__ rmsw,
                           const float* __restrict__ tbl, bf16* __restrict__ dst,
                           float outscale) {
    const int T = 2048;
    int wv = blockIdx.x * 4 + (threadIdx.x >> 6); // over B*T*H, h fastest
    int lane = threadIdx.x & 63;
    int h = wv & 15, bt = wv >> 4;
    int t = bt & (T - 1), b_ = bt >> 11;
    const float* p = src + (size_t)bt * 2048 + h * 128;
    float a = p[lane], b = p[lane + 64];
    float cs = tbl[t * 128 + lane], sn = tbl[t * 128 + 64 + lane];
    float r1 = a * cs - b * sn, r2 = a * sn + b * cs;
    float ss = r1 * r1 + r2 * r2;
#pragma unroll
    for (int d = 1; d < 64; d <<= 1) ss += __shfl_xor(ss, d, 64);
    float rs = rsqrtf(ss * (1.0f / 128.0f) + 1e-5f);
    size_t o = ((size_t)(b_ * 16 + h) * T + t) * 128;
    dst[o + lane] = __float2bfloat16(r1 * rs * rmsw[lane] * outscale);
    dst[o + lane + 64] = __float2bfloat16(r2 * rs * rmsw[lane + 64] * outscale);
}

// ---------------- V transpose: fp32 [B*T][2048] -> bf16 Vt [BH][128][T] ----------------
__global__ void k_vtrans(const float* __restrict__ V, bf16* __restrict__ Vt) {
    const int T = 2048;
    __shared__ float tile[32][33];
    int bh = blockIdx.z, b_ = bh >> 4, h = bh & 15;
    int t0 = blockIdx.x * 32, d0 = blockIdx.y * 32;
    int tx = threadIdx.x, ty = threadIdx.y; // 32 x 8
#pragma unroll
    for (int i = 0; i < 4; i++)
        tile[ty + 8 * i][tx] = V[((size_t)(b_ * T + t0 + ty + 8 * i)) * 2048 + h * 128 + d0 + tx];
    __syncthreads();
#pragma unroll
    for (int i = 0; i < 4; i++)
        Vt[((size_t)bh * 128 + d0 + ty + 8 * i) * T + t0 + tx] = __float2bfloat16(tile[tx][ty + 8 * i]);
}

// ---------------- causal flash attention v3 ----------------
// Q,K [BH][T][128], Vt [BH][128][T] -> Y fp32 [BH][T][128]
// - K/V staged in LDS (shared by 4 waves), double-buffered, issue-before-compute.
// - XOR-swizzled LDS (linear gload_lds dest + inverse-swizzled global source + swizzled read).
// - Swapped QK^T: S^T = mfma(K, Q) -> each lane owns one q-row -> in-lane softmax reduce.
// - Heavy-first causal scheduling + XCD-grouped heads (XCD = wg%8 = bh%8).
__global__ __launch_bounds__(256) void k_attn(
    const bf16* __restrict__ Q, const bf16* __restrict__ K,
    const bf16* __restrict__ Vt, float* __restrict__ Y) {
    const int T = 2048;
    __shared__ __align__(16) bf16 KsB[2][64 * 128];
    __shared__ __align__(16) bf16 VsB[2][128 * 64];
    __shared__ __align__(16) bf16 Ps[64 * 72];
    int lane = threadIdx.x & 63, wave = threadIdx.x >> 6;
    int g = lane >> 4, c = lane & 15;
    int wg = blockIdx.x;
    int bh = wg & 31;          // XCD = bh%8 -> 4 heads per XCD (K+V = 4MB = one L2)
    int qt = 31 - (wg >> 5);   // heavy q-tiles launch first
    int q0 = qt * 64;
    const bf16* Qb = Q + (size_t)bh * T * 128;
    const bf16* Kb = K + (size_t)bh * T * 128;
    const bf16* Vb = Vt + (size_t)bh * 128 * T;

    // Q fragments (B-operand; lane provides q-col = c)
    int qrow = q0 + wave * 16 + c;
    bf16x8 qf[4];
#pragma unroll
    for (int kk = 0; kk < 4; kk++)
        qf[kk] = *reinterpret_cast<const bf16x8*>(&Qb[(size_t)qrow * 128 + kk * 32 + g * 8]);

    // staging lane constants (pre-swizzled global source, rule #21)
    int kli = lane >> 4;                       // row-in-chunk for K (4 rows/chunk)
    int vli = lane >> 3;                       // row-in-chunk for V (8 rows/chunk)
    int vlu = (lane & 7) ^ (vli & 7);          // V logical 16B-unit

    auto stage = [&](int kv0, int b) {
#pragma unroll
        for (int i = 0; i < 4; i++) {
            int ch = wave * 4 + i;
            int krow = ch * 4 + kli;
            int klu = (lane & 15) ^ (krow & 7);
            gload16(&Kb[(size_t)(kv0 + krow) * 128 + klu * 8], &KsB[b][ch * 512]);
            int vrow = ch * 8 + vli;
            gload16(&Vb[(size_t)vrow * T + kv0 + vlu * 8], &VsB[b][ch * 512]);
        }
    };

    f32x4 acc[8];
#pragma unroll
    for (int i = 0; i < 8; i++) acc[i] = {0.f, 0.f, 0.f, 0.f};
    float m = -INFINITY, l = 0.f;  // per-lane softmax state for q-row = qrow

    int ntiles = qt + 1;
    stage(0, 0);
    __syncthreads();
    int cur = 0;
    for (int it = 0; it < ntiles; ++it) {
        int kv0 = it * 64;
        if (it + 1 < ntiles) stage(kv0 + 64, cur ^ 1);  // prefetch overlaps compute
        const bf16* Ks = KsB[cur];
        const bf16* Vs = VsB[cur];

        // ---- S^T = K * Q^T (A = K rows = kv, B = Q cols = q) ----
        f32x4 s[4];
#pragma unroll
        for (int nf = 0; nf < 4; nf++) s[nf] = {0.f, 0.f, 0.f, 0.f};
#pragma unroll
        for (int nf = 0; nf < 4; nf++)
#pragma unroll
            for (int kk = 0; kk < 4; kk++) {
                int pu = (kk * 4 + g) ^ (c & 7);
                bf16x8 kf = *reinterpret_cast<const bf16x8*>(&Ks[(nf * 16 + c) * 128 + pu * 8]);
                s[nf] = __builtin_amdgcn_mfma_f32_16x16x32_bf16(kf, qf[kk], s[nf], 0, 0, 0);
            }
        // lane holds S[q=qrow][kv = kv0 + nf*16 + g*4 + r]
        if (it == ntiles - 1) {
#pragma unroll
            for (int nf = 0; nf < 4; nf++)
#pragma unroll
                for (int r = 0; r < 4; r++)
                    if (kv0 + nf * 16 + g * 4 + r > qrow) s[nf][r] = -1e30f;
        }
        // ---- in-lane online softmax (one q-row per lane) ----
        float mx = -INFINITY;
#pragma unroll
        for (int nf = 0; nf < 4; nf++)
#pragma unroll
            for (int r = 0; r < 4; r++) mx = fmaxf(mx, s[nf][r]);
        mx = fmaxf(mx, __shfl_xor(mx, 16, 64));
        mx = fmaxf(mx, __shfl_xor(mx, 32, 64));
        float mnew = fmaxf(m, mx);
        float alpha = __expf(m - mnew);
        m = mnew;
        float rsum = 0.f;
#pragma unroll
        for (int nf = 0; nf < 4; nf++)
#pragma unroll
            for (int r = 0; r < 4; r++) {
                float p = __expf(s[nf][r] - mnew);
                s[nf][r] = p;
                rsum += p;
            }
        rsum += __shfl_xor(rsum, 16, 64);
        rsum += __shfl_xor(rsum, 32, 64);
        l = l * alpha + rsum;
        // ---- redistribute alpha to acc rows (acc row q16 = g*4+r lives at lane q16) ----
        float al[4];
#pragma unroll
        for (int r = 0; r < 4; r++) al[r] = __shfl(alpha, g * 4 + r, 64);
#pragma unroll
        for (int nf = 0; nf < 8; nf++)
#pragma unroll
            for (int r = 0; r < 4; r++) acc[nf][r] *= al[r];
        // ---- P -> LDS [q][kv] (wave-private rows; lgkmcnt orders write->read) ----
#pragma unroll
        for (int nf = 0; nf < 4; nf++) {
            union { bf16 h[4]; uint2 u; } pk;
#pragma unroll
            for (int r = 0; r < 4; r++) pk.h[r] = __float2bfloat16(s[nf][r]);
            *reinterpret_cast<uint2*>(&Ps[(wave * 16 + c) * 72 + nf * 16 + g * 4]) = pk.u;
        }
        // ---- PV: A = P rows = q, B = V^T rows = d (swizzled read) ----
#pragma unroll
        for (int kk2 = 0; kk2 < 2; kk2++) {
            bf16x8 pf = *reinterpret_cast<const bf16x8*>(&Ps[(wave * 16 + c) * 72 + kk2 * 32 + g * 8]);
#pragma unroll
            for (int nf = 0; nf < 8; nf++) {
                int pu = (kk2 * 4 + g) ^ (c & 7);
                bf16x8 vf = *reinterpret_cast<const bf16x8*>(&Vs[(nf * 16 + c) * 64 + pu * 8]);
                acc[nf] = __builtin_amdgcn_mfma_f32_16x16x32_bf16(pf, vf, acc[nf], 0, 0, 0);
            }
        }
        __syncthreads();  // next-tile stage complete + all waves done reading cur
        cur ^= 1;
    }
    // epilogue: 1/l redistribution + store
    float inv = 1.0f / l;
    float iv[4];
#pragma unroll
    for (int r = 0; r < 4; r++) iv[r] = __shfl(inv, g * 4 + r, 64);
#pragma unroll
    for (int r = 0; r < 4; r++) {
        size_t row = q0 + wave * 16 + g * 4 + r;
#pragma unroll
        for (int nf = 0; nf < 8; nf++)
            Y[(size_t)bh * T * 128 + row * 128 + nf * 16 + c] = acc[nf][r] * iv[r];
    }
}

// ---------------- o-norm + silu(gate) gating -> bf16 [B*T][2048] ----------------
__global__ void k_finalize(const float* __restrict__ Y, const float* __restrict__ gate,
                           const float* __restrict__ ow, bf16* __restrict__ out) {
    const int T = 2048;
    int wv = blockIdx.x * 4 + (threadIdx.x >> 6); // over BH*T
    int lane = threadIdx.x & 63;
    int t = wv & (T - 1), bh = wv >> 11;
    int b_ = bh >> 4, h = bh & 15;
    const float* y = Y + (size_t)wv * 128;
    float y1 = y[lane], y2 = y[lane + 64];
    float ss = y1 * y1 + y2 * y2;
#pragma unroll
    for (int d = 1; d < 64; d <<= 1) ss += __shfl_xor(ss, d, 64);
    float rs = rsqrtf(ss * (1.0f / 128.0f) + 1e-5f);
    size_t gi = ((size_t)(b_ * T + t)) * 2048 + h * 128;
    float g1 = gate[gi + lane], g2 = gate[gi + lane + 64];
    g1 = g1 / (1.f + __expf(-g1));
    g2 = g2 / (1.f + __expf(-g2));
    out[gi + lane] = __float2bfloat16(y1 * rs * ow[lane] * g1);
    out[gi + lane + 64] = __float2bfloat16(y2 * rs * ow[lane + 64] * g2);
}

extern "C" void kernel_launch(void* const* d_in, const int* in_sizes, int n_in,
                              void* d_out, int out_size, void* d_ws, size_t ws_size,
                              hipStream_t stream) {
    const float* x  = (const float*)d_in[0];
    const float* Wq = (const float*)d_in[1];
    const float* Wk = (const float*)d_in[2];
    const float* Wv = (const float*)d_in[3];
    const float* Wg = (const float*)d_in[4];
    const float* Wo = (const float*)d_in[5];
    const float* qw = (const float*)d_in[6];
    const float* kw = (const float*)d_in[7];
    const float* ow = (const float*)d_in[8];

    const size_t M = 4096, HID = 2048;
    char* w = (char*)d_ws;
    bf16*  xb    = (bf16*)(w);                     // 16,777,216 B
    bf16*  Wt    = (bf16*)(w + 16777216);          // 41,943,040 B  [5][2048][2048]
    float* qkvg  = (float*)(w + 58720256);         // 134,217,728 B [4][4096][2048]
    bf16*  q_att = (bf16*)(w + 192937984);         // 16,777,216 B  [32][2048][128]
    bf16*  k_att = (bf16*)(w + 209715200);         // 16,777,216 B
    bf16*  vt    = (bf16*)(w + 226492416);         // 16,777,216 B  [32][128][2048]
    float* tbl   = (float*)(w + 243269632);        // 1,048,576 B   [2048][128]
    float* y_att = qkvg;                           // reuse q slot (dead after rope)
    bf16*  yg    = (bf16*)(qkvg + M * HID);        // reuse k slot (dead after rope)

    k_cvt_bf16<<<8192, 256, 0, stream>>>(x, xb, (int)(M * HID / 4));
    k_rope_tbl<<<512, 256, 0, stream>>>(tbl);
    k_wtrans<<<dim3(64, 64, 5), dim3(32, 8), 0, stream>>>(Wq, Wk, Wv, Wg, Wo, Wt);
    // fused Q/K/V/Gate projection
    k_gemm<<<dim3(32, 16, 4), 256, 0, stream>>>(xb, Wt, qkvg, (int)M, 2048, 2048);
    // rope + rms (+ fold 1/sqrt(D) into q)
    k_rope_rms<<<16384, 256, 0, stream>>>(qkvg, qw, tbl, q_att, 0.08838834764831845f);
    k_rope_rms<<<16384, 256, 0, stream>>>(qkvg + M * HID, kw, tbl, k_att, 1.0f);
    k_vtrans<<<dim3(64, 4, 32), dim3(32, 8), 0, stream>>>(qkvg + 2 * M * HID, vt);
    k_attn<<<1024, 256, 0, stream>>>(q_att, k_att, vt, y_att);
    k_finalize<<<16384, 256, 0, stream>>>(y_att, qkvg + 3 * M * HID, ow, yg);
    // output projection
    k_gemm<<<dim3(32, 16, 1), 256, 0, stream>>>(yg, Wt + (size_t)4 * 2048 * 2048, (float*)d_out,
                                                (int)M, 2048, 2048);
}

// Round 4
// 342.283 us; speedup vs baseline: 1.7561x; 1.1665x over previous
//
#include <hip/hip_runtime.h>
#include <hip/hip_bf16.h>
#include <stdint.h>

typedef __bf16 bf16x8 __attribute__((ext_vector_type(8)));
typedef float f32x4 __attribute__((ext_vector_type(4)));
typedef __hip_bfloat16 bf16;

__device__ __forceinline__ void gload16(const void* g, void* l) {
    __builtin_amdgcn_global_load_lds(
        (const __attribute__((address_space(1))) uint32_t*)g,
        (__attribute__((address_space(3))) uint32_t*)l,
        16, 0, 0);
}

// ---------------- elementwise convert fp32 -> bf16 (x) ----------------
__global__ void k_cvt_bf16(const float* __restrict__ in, bf16* __restrict__ out, int n4) {
    int i = blockIdx.x * blockDim.x + threadIdx.x;
    if (i >= n4) return;
    float4 v = reinterpret_cast<const float4*>(in)[i];
    union { bf16 h[4]; uint2 u; } pk;
    pk.h[0] = __float2bfloat16(v.x);
    pk.h[1] = __float2bfloat16(v.y);
    pk.h[2] = __float2bfloat16(v.z);
    pk.h[3] = __float2bfloat16(v.w);
    reinterpret_cast<uint2*>(out)[i] = pk.u;
}

// ---------------- rope cos/sin table [T][128] (cos j | sin j) ----------------
__global__ void k_rope_tbl(float* __restrict__ tbl) {
    int i = blockIdx.x * blockDim.x + threadIdx.x; // T*64
    int t = i >> 6, j = i & 63;
    float inv = powf(10000.0f, -(float)j * (1.0f / 64.0f));
    float f = (float)t * inv;
    tbl[t * 128 + j] = cosf(f);
    tbl[t * 128 + 64 + j] = sinf(f);
}

// ---------------- weight transpose + convert: W[k][n] fp32 -> Wt[n][k] bf16 ----------------
__global__ void k_wtrans(const float* __restrict__ w0, const float* __restrict__ w1,
                         const float* __restrict__ w2, const float* __restrict__ w3,
                         const float* __restrict__ w4, bf16* __restrict__ out) {
    __shared__ float tile[32][33];
    const float* srcs[5] = {w0, w1, w2, w3, w4};
    const float* src = srcs[blockIdx.z];
    bf16* dst = out + (size_t)blockIdx.z * 2048 * 2048;
    int k0 = blockIdx.x * 32, n0 = blockIdx.y * 32;
    int tx = threadIdx.x, ty = threadIdx.y; // 32 x 8
#pragma unroll
    for (int i = 0; i < 4; i++)
        tile[ty + 8 * i][tx] = src[(size_t)(k0 + ty + 8 * i) * 2048 + n0 + tx];
    __syncthreads();
#pragma unroll
    for (int i = 0; i < 4; i++)
        dst[(size_t)(n0 + ty + 8 * i) * 2048 + k0 + tx] = __float2bfloat16(tile[tx][ty + 8 * i]);
}

// ---------------- GEMM 128x128 (m97-structure), used for the output projection ----------------
__global__ __launch_bounds__(256) void k_gemm(
    const bf16* __restrict__ A, const bf16* __restrict__ Bt, float* __restrict__ C,
    int M, int N, int K) {
    __shared__ __align__(16) bf16 As[128 * 64];
    __shared__ __align__(16) bf16 Bs[128 * 64];
    int lane = threadIdx.x & 63, wave = threadIdx.x >> 6;
    int g = lane >> 4, cc = lane & 15;
    int wr = wave >> 1, wc = wave & 1;
    size_t m0 = (size_t)blockIdx.x * 128, n0 = (size_t)blockIdx.y * 128;
    const bf16* Ab = A + m0 * K;
    const bf16* Bb = Bt + (size_t)blockIdx.z * N * K + n0 * K;
    float* Cb = C + (size_t)blockIdx.z * M * N + m0 * N + n0;

    f32x4 acc[4][4];
#pragma unroll
    for (int i = 0; i < 4; i++)
#pragma unroll
        for (int j = 0; j < 4; j++) acc[i][j] = {0.f, 0.f, 0.f, 0.f};

    int scol = (lane & 7) * 8;
    for (int k0 = 0; k0 < K; k0 += 64) {
#pragma unroll
        for (int i = 0; i < 4; i++) {
            int ch = wave * 4 + i;
            int row = ch * 8 + (lane >> 3);
            gload16(&Ab[(size_t)row * K + k0 + scol], &As[ch * 512]);
            gload16(&Bb[(size_t)row * K + k0 + scol], &Bs[ch * 512]);
        }
        __syncthreads();
#pragma unroll
        for (int kk = 0; kk < 2; kk++) {
            bf16x8 af[4], bfr[4];
#pragma unroll
            for (int m = 0; m < 4; m++)
                af[m] = *reinterpret_cast<const bf16x8*>(&As[(wr * 64 + m * 16 + cc) * 64 + kk * 32 + g * 8]);
#pragma unroll
            for (int n = 0; n < 4; n++)
                bfr[n] = *reinterpret_cast<const bf16x8*>(&Bs[(wc * 64 + n * 16 + cc) * 64 + kk * 32 + g * 8]);
#pragma unroll
            for (int m = 0; m < 4; m++)
#pragma unroll
                for (int n = 0; n < 4; n++)
                    acc[m][n] = __builtin_amdgcn_mfma_f32_16x16x32_bf16(af[m], bfr[n], acc[m][n], 0, 0, 0);
        }
        __syncthreads();
    }
#pragma unroll
    for (int m = 0; m < 4; m++)
#pragma unroll
        for (int n = 0; n < 4; n++)
#pragma unroll
            for (int r = 0; r < 4; r++) {
                size_t row = wr * 64 + m * 16 + g * 4 + r;
                Cb[row * N + (wc * 64 + n * 16 + cc)] = acc[m][n][r];
            }
}

// ---------------- GEMM 256x256, 8-phase counted-vmcnt schedule (m201-style) ----------------
// C[z][M][N] = A[M][K] @ Bt[z][N][K]^T. 512 threads = 8 waves (2M x 4N), BK=64.
// LDS 128KB: [2 buf][4 region: A0,A1,B0,B1][128 rows x 64 cols bf16], XOR-swizzled
// (16B unit ^= row&7; linear gload_lds dest + inverse-swizzled global src + swizzled read).
// Region death schedule per K-tile t (4 phases): A0@ph1, A1@ph2, B0@ph3, B1@ph4.
// Staging: ph1 -> tile(t+1).B1; ph2/3/4 -> tile(t+2).{A0,A1,B0}. vmcnt(6) at ph4.
#define QUAD(mh, kk, bvec)                                                              \
    do {                                                                                \
        _Pragma("unroll") for (int m_ = 0; m_ < 4; m_++)                                \
            _Pragma("unroll") for (int n_ = 0; n_ < 4; n_++)                            \
                acc[(mh)*4 + m_][n_] = __builtin_amdgcn_mfma_f32_16x16x32_bf16(         \
                    afr[(mh)*4 + m_][kk], bvec[n_], acc[(mh)*4 + m_][n_], 0, 0, 0);     \
    } while (0)

__global__ __launch_bounds__(512, 2) void k_gemm256(
    const bf16* __restrict__ A, const bf16* __restrict__ Bt, float* __restrict__ C,
    int M, int N, int K) {
    __shared__ __align__(16) bf16 lds[2][4][128 * 64];
    const int tid = threadIdx.x;
    const int lane = tid & 63, wave = tid >> 6;
    const int g = lane >> 4, c = lane & 15, cx = c & 7;
    const int wr = wave >> 2, wc = wave & 3;  // 2M x 4N
    const size_t m0 = (size_t)blockIdx.x * 256, n0 = (size_t)blockIdx.y * 256;
    const bf16* Ab = A + m0 * K;
    const bf16* Bb = Bt + (size_t)blockIdx.z * (size_t)N * K + n0 * K;
    float* Cb = C + (size_t)blockIdx.z * (size_t)M * N + m0 * N + n0;
    const int nt = K >> 6;

    // staging constants: region = 128 rows x 64 cols; 2 rounds x 512 thr x 16B
    const int srow = tid >> 3;                        // 0..63 (round adds +64)
    const int scol = ((tid & 7) ^ (srow & 7)) * 8;    // inverse-swizzled source col

    auto stage = [&](int u, int rg) {
        if (u >= nt) return;
        const bf16* srcb = (rg < 2) ? Ab : Bb;
        const int rowbase = (rg & 1) << 7;
        bf16* dst = &lds[u & 1][rg][wave * 512];      // wave-uniform dest
        const size_t k0 = (size_t)u << 6;
        gload16(&srcb[(size_t)(rowbase + srow) * K + k0 + scol], dst);
        gload16(&srcb[(size_t)(rowbase + 64 + srow) * K + k0 + scol], dst + 4096);
    };

    f32x4 acc[8][4];
#pragma unroll
    for (int i = 0; i < 8; i++)
#pragma unroll
        for (int j = 0; j < 4; j++) acc[i][j] = {0.f, 0.f, 0.f, 0.f};

    // prologue: tile0 all 4 halves (8 loads), tile1 A0,A1,B0 (6 loads)
    stage(0, 0); stage(0, 1); stage(0, 2); stage(0, 3);
    stage(1, 0); stage(1, 1); stage(1, 2);
    asm volatile("s_waitcnt vmcnt(6)" ::: "memory");
    __builtin_amdgcn_s_barrier();

    bf16x8 afr[8][2], b0[4], b1[4];
    const int browbase = (wc & 1) * 64;
    for (int t = 0; t < nt; ++t) {
        const bf16* bA = &lds[t & 1][wr][0];
        const bf16* bB = &lds[t & 1][2 + (wc >> 1)][0];
        // ---- ph1: read all A frags + B kk0; stage tile(t+1).B1 ----
#pragma unroll
        for (int m_ = 0; m_ < 8; m_++)
#pragma unroll
            for (int kk_ = 0; kk_ < 2; kk_++)
                afr[m_][kk_] = *reinterpret_cast<const bf16x8*>(
                    bA + (m_ * 16 + c) * 64 + ((kk_ * 4 + g) ^ cx) * 8);
#pragma unroll
        for (int n_ = 0; n_ < 4; n_++)
            b0[n_] = *reinterpret_cast<const bf16x8*>(
                bB + (browbase + n_ * 16 + c) * 64 + (g ^ cx) * 8);
        stage(t + 1, 3);
        __builtin_amdgcn_s_barrier();
        asm volatile("s_waitcnt lgkmcnt(0)" ::: "memory");
        __builtin_amdgcn_sched_barrier(0);
        __builtin_amdgcn_s_setprio(1);
        QUAD(0, 0, b0);
        __builtin_amdgcn_s_setprio(0);
        __builtin_amdgcn_s_barrier();
        // ---- ph2: stage tile(t+2).A0 ----
        stage(t + 2, 0);
        __builtin_amdgcn_s_barrier();
        __builtin_amdgcn_s_setprio(1);
        QUAD(1, 0, b0);
        __builtin_amdgcn_s_setprio(0);
        __builtin_amdgcn_s_barrier();
        // ---- ph3: read B kk1; stage tile(t+2).A1 ----
#pragma unroll
        for (int n_ = 0; n_ < 4; n_++)
            b1[n_] = *reinterpret_cast<const bf16x8*>(
                bB + (browbase + n_ * 16 + c) * 64 + ((4 + g) ^ cx) * 8);
        stage(t + 2, 1);
        __builtin_amdgcn_s_barrier();
        asm volatile("s_waitcnt lgkmcnt(0)" ::: "memory");
        __builtin_amdgcn_sched_barrier(0);
        __builtin_amdgcn_s_setprio(1);
        QUAD(0, 1, b1);
        __builtin_amdgcn_s_setprio(0);
        __builtin_amdgcn_s_barrier();
        // ---- ph4: stage tile(t+2).B0; counted vmcnt before barrier ----
        stage(t + 2, 2);
        if (t < nt - 2) asm volatile("s_waitcnt vmcnt(6)" ::: "memory");
        else            asm volatile("s_waitcnt vmcnt(0)" ::: "memory");
        __builtin_amdgcn_s_barrier();
        __builtin_amdgcn_s_setprio(1);
        QUAD(1, 1, b1);
        __builtin_amdgcn_s_setprio(0);
        __builtin_amdgcn_s_barrier();
    }
    // epilogue
#pragma unroll
    for (int m_ = 0; m_ < 8; m_++)
#pragma unroll
        for (int n_ = 0; n_ < 4; n_++)
#pragma unroll
            for (int r_ = 0; r_ < 4; r_++) {
                size_t row = wr * 128 + m_ * 16 + g * 4 + r_;
                Cb[row * N + wc * 64 + n_ * 16 + c] = acc[m_][n_][r_];
            }
}

// ---------------- RoPE + per-head RMS norm, fp32 [B*T][2048] -> bf16 [BH][T][128] ----------------
__global__ void k_rope_rms(const float* __restrict__ src, const float* __restrict__ rmsw,
                           const float* __restrict__ tbl, bf16* __restrict__ dst,
                           float outscale) {
    const int T = 2048;
    int wv = blockIdx.x * 4 + (threadIdx.x >> 6); // over B*T*H, h fastest
    int lane = threadIdx.x & 63;
    int h = wv & 15, bt = wv >> 4;
    int t = bt & (T - 1), b_ = bt >> 11;
    const float* p = src + (size_t)bt * 2048 + h * 128;
    float a = p[lane], b = p[lane + 64];
    float cs = tbl[t * 128 + lane], sn = tbl[t * 128 + 64 + lane];
    float r1 = a * cs - b * sn, r2 = a * sn + b * cs;
    float ss = r1 * r1 + r2 * r2;
#pragma unroll
    for (int d = 1; d < 64; d <<= 1) ss += __shfl_xor(ss, d, 64);
    float rs = rsqrtf(ss * (1.0f / 128.0f) + 1e-5f);
    size_t o = ((size_t)(b_ * 16 + h) * T + t) * 128;
    dst[o + lane] = __float2bfloat16(r1 * rs * rmsw[lane] * outscale);
    dst[o + lane + 64] = __float2bfloat16(r2 * rs * rmsw[lane + 64] * outscale);
}

// ---------------- V transpose: fp32 [B*T][2048] -> bf16 Vt [BH][128][T] ----------------
__global__ void k_vtrans(const float* __restrict__ V, bf16* __restrict__ Vt) {
    const int T = 2048;
    __shared__ float tile[32][33];
    int bh = blockIdx.z, b_ = bh >> 4, h = bh & 15;
    int t0 = blockIdx.x * 32, d0 = blockIdx.y * 32;
    int tx = threadIdx.x, ty = threadIdx.y; // 32 x 8
#pragma unroll
    for (int i = 0; i < 4; i++)
        tile[ty + 8 * i][tx] = V[((size_t)(b_ * T + t0 + ty + 8 * i)) * 2048 + h * 128 + d0 + tx];
    __syncthreads();
#pragma unroll
    for (int i = 0; i < 4; i++)
        Vt[((size_t)bh * 128 + d0 + ty + 8 * i) * T + t0 + tx] = __float2bfloat16(tile[tx][ty + 8 * i]);
}

// ---------------- causal flash attention v3 ----------------
__global__ __launch_bounds__(256) void k_attn(
    const bf16* __restrict__ Q, const bf16* __restrict__ K,
    const bf16* __restrict__ Vt, float* __restrict__ Y) {
    const int T = 2048;
    __shared__ __align__(16) bf16 KsB[2][64 * 128];
    __shared__ __align__(16) bf16 VsB[2][128 * 64];
    __shared__ __align__(16) bf16 Ps[64 * 72];
    int lane = threadIdx.x & 63, wave = threadIdx.x >> 6;
    int g = lane >> 4, c = lane & 15;
    int wg = blockIdx.x;
    int bh = wg & 31;          // XCD = bh%8 -> 4 heads per XCD (K+V = 4MB = one L2)
    int qt = 31 - (wg >> 5);   // heavy q-tiles launch first
    int q0 = qt * 64;
    const bf16* Qb = Q + (size_t)bh * T * 128;
    const bf16* Kb = K + (size_t)bh * T * 128;
    const bf16* Vb = Vt + (size_t)bh * 128 * T;

    int qrow = q0 + wave * 16 + c;
    bf16x8 qf[4];
#pragma unroll
    for (int kk = 0; kk < 4; kk++)
        qf[kk] = *reinterpret_cast<const bf16x8*>(&Qb[(size_t)qrow * 128 + kk * 32 + g * 8]);

    int kli = lane >> 4;
    int vli = lane >> 3;
    int vlu = (lane & 7) ^ (vli & 7);

    auto stage = [&](int kv0, int b) {
#pragma unroll
        for (int i = 0; i < 4; i++) {
            int ch = wave * 4 + i;
            int krow = ch * 4 + kli;
            int klu = (lane & 15) ^ (krow & 7);
            gload16(&Kb[(size_t)(kv0 + krow) * 128 + klu * 8], &KsB[b][ch * 512]);
            int vrow = ch * 8 + vli;
            gload16(&Vb[(size_t)vrow * T + kv0 + vlu * 8], &VsB[b][ch * 512]);
        }
    };

    f32x4 acc[8];
#pragma unroll
    for (int i = 0; i < 8; i++) acc[i] = {0.f, 0.f, 0.f, 0.f};
    float m = -INFINITY, l = 0.f;

    int ntiles = qt + 1;
    stage(0, 0);
    __syncthreads();
    int cur = 0;
    for (int it = 0; it < ntiles; ++it) {
        int kv0 = it * 64;
        if (it + 1 < ntiles) stage(kv0 + 64, cur ^ 1);
        const bf16* Ks = KsB[cur];
        const bf16* Vs = VsB[cur];

        f32x4 s[4];
#pragma unroll
        for (int nf = 0; nf < 4; nf++) s[nf] = {0.f, 0.f, 0.f, 0.f};
#pragma unroll
        for (int nf = 0; nf < 4; nf++)
#pragma unroll
            for (int kk = 0; kk < 4; kk++) {
                int pu = (kk * 4 + g) ^ (c & 7);
                bf16x8 kf = *reinterpret_cast<const bf16x8*>(&Ks[(nf * 16 + c) * 128 + pu * 8]);
                s[nf] = __builtin_amdgcn_mfma_f32_16x16x32_bf16(kf, qf[kk], s[nf], 0, 0, 0);
            }
        if (it == ntiles - 1) {
#pragma unroll
            for (int nf = 0; nf < 4; nf++)
#pragma unroll
                for (int r = 0; r < 4; r++)
                    if (kv0 + nf * 16 + g * 4 + r > qrow) s[nf][r] = -1e30f;
        }
        float mx = -INFINITY;
#pragma unroll
        for (int nf = 0; nf < 4; nf++)
#pragma unroll
            for (int r = 0; r < 4; r++) mx = fmaxf(mx, s[nf][r]);
        mx = fmaxf(mx, __shfl_xor(mx, 16, 64));
        mx = fmaxf(mx, __shfl_xor(mx, 32, 64));
        float mnew = fmaxf(m, mx);
        float alpha = __expf(m - mnew);
        m = mnew;
        float rsum = 0.f;
#pragma unroll
        for (int nf = 0; nf < 4; nf++)
#pragma unroll
            for (int r = 0; r < 4; r++) {
                float p = __expf(s[nf][r] - mnew);
                s[nf][r] = p;
                rsum += p;
            }
        rsum += __shfl_xor(rsum, 16, 64);
        rsum += __shfl_xor(rsum, 32, 64);
        l = l * alpha + rsum;
        float al[4];
#pragma unroll
        for (int r = 0; r < 4; r++) al[r] = __shfl(alpha, g * 4 + r, 64);
#pragma unroll
        for (int nf = 0; nf < 8; nf++)
#pragma unroll
            for (int r = 0; r < 4; r++) acc[nf][r] *= al[r];
#pragma unroll
        for (int nf = 0; nf < 4; nf++) {
            union { bf16 h[4]; uint2 u; } pk;
#pragma unroll
            for (int r = 0; r < 4; r++) pk.h[r] = __float2bfloat16(s[nf][r]);
            *reinterpret_cast<uint2*>(&Ps[(wave * 16 + c) * 72 + nf * 16 + g * 4]) = pk.u;
        }
#pragma unroll
        for (int kk2 = 0; kk2 < 2; kk2++) {
            bf16x8 pf = *reinterpret_cast<const bf16x8*>(&Ps[(wave * 16 + c) * 72 + kk2 * 32 + g * 8]);
#pragma unroll
            for (int nf = 0; nf < 8; nf++) {
                int pu = (kk2 * 4 + g) ^ (c & 7);
                bf16x8 vf = *reinterpret_cast<const bf16x8*>(&Vs[(nf * 16 + c) * 64 + pu * 8]);
                acc[nf] = __builtin_amdgcn_mfma_f32_16x16x32_bf16(pf, vf, acc[nf], 0, 0, 0);
            }
        }
        __syncthreads();
        cur ^= 1;
    }
    float inv = 1.0f / l;
    float iv[4];
#pragma unroll
    for (int r = 0; r < 4; r++) iv[r] = __shfl(inv, g * 4 + r, 64);
#pragma unroll
    for (int r = 0; r < 4; r++) {
        size_t row = q0 + wave * 16 + g * 4 + r;
#pragma unroll
        for (int nf = 0; nf < 8; nf++)
            Y[(size_t)bh * T * 128 + row * 128 + nf * 16 + c] = acc[nf][r] * iv[r];
    }
}

// ---------------- o-norm + silu(gate) gating -> bf16 [B*T][2048] ----------------
__global__ void k_finalize(const float* __restrict__ Y, const float* __restrict__ gate,
                           const float* __restrict__ ow, bf16* __restrict__ out) {
    const int T = 2048;
    int wv = blockIdx.x * 4 + (threadIdx.x >> 6); // over BH*T
    int lane = threadIdx.x & 63;
    int t = wv & (T - 1), bh = wv >> 11;
    int b_ = bh >> 4, h = bh & 15;
    const float* y = Y + (size_t)wv * 128;
    float y1 = y[lane], y2 = y[lane + 64];
    float ss = y1 * y1 + y2 * y2;
#pragma unroll
    for (int d = 1; d < 64; d <<= 1) ss += __shfl_xor(ss, d, 64);
    float rs = rsqrtf(ss * (1.0f / 128.0f) + 1e-5f);
    size_t gi = ((size_t)(b_ * T + t)) * 2048 + h * 128;
    float g1 = gate[gi + lane], g2 = gate[gi + lane + 64];
    g1 = g1 / (1.f + __expf(-g1));
    g2 = g2 / (1.f + __expf(-g2));
    out[gi + lane] = __float2bfloat16(y1 * rs * ow[lane] * g1);
    out[gi + lane + 64] = __float2bfloat16(y2 * rs * ow[lane + 64] * g2);
}

extern "C" void kernel_launch(void* const* d_in, const int* in_sizes, int n_in,
                              void* d_out, int out_size, void* d_ws, size_t ws_size,
                              hipStream_t stream) {
    const float* x  = (const float*)d_in[0];
    const float* Wq = (const float*)d_in[1];
    const float* Wk = (const float*)d_in[2];
    const float* Wv = (const float*)d_in[3];
    const float* Wg = (const float*)d_in[4];
    const float* Wo = (const float*)d_in[5];
    const float* qw = (const float*)d_in[6];
    const float* kw = (const float*)d_in[7];
    const float* ow = (const float*)d_in[8];

    const size_t M = 4096, HID = 2048;
    char* w = (char*)d_ws;
    bf16*  xb    = (bf16*)(w);                     // 16,777,216 B
    bf16*  Wt    = (bf16*)(w + 16777216);          // 41,943,040 B  [5][2048][2048]
    float* qkvg  = (float*)(w + 58720256);         // 134,217,728 B [4][4096][2048]
    bf16*  q_att = (bf16*)(w + 192937984);         // 16,777,216 B  [32][2048][128]
    bf16*  k_att = (bf16*)(w + 209715200);         // 16,777,216 B
    bf16*  vt    = (bf16*)(w + 226492416);         // 16,777,216 B  [32][128][2048]
    float* tbl   = (float*)(w + 243269632);        // 1,048,576 B   [2048][128]
    float* y_att = qkvg;                           // reuse q slot (dead after rope)
    bf16*  yg    = (bf16*)(qkvg + M * HID);        // reuse k slot (dead after rope)

    k_cvt_bf16<<<8192, 256, 0, stream>>>(x, xb, (int)(M * HID / 4));
    k_rope_tbl<<<512, 256, 0, stream>>>(tbl);
    k_wtrans<<<dim3(64, 64, 5), dim3(32, 8), 0, stream>>>(Wq, Wk, Wv, Wg, Wo, Wt);
    // fused Q/K/V/Gate projection: 256x256 8-phase template
    k_gemm256<<<dim3(16, 8, 4), 512, 0, stream>>>(xb, Wt, qkvg, (int)M, 2048, 2048);
    // rope + rms (+ fold 1/sqrt(D) into q)
    k_rope_rms<<<16384, 256, 0, stream>>>(qkvg, qw, tbl, q_att, 0.08838834764831845f);
    k_rope_rms<<<16384, 256, 0, stream>>>(qkvg + M * HID, kw, tbl, k_att, 1.0f);
    k_vtrans<<<dim3(64, 4, 32), dim3(32, 8), 0, stream>>>(qkvg + 2 * M * HID, vt);
    k_attn<<<1024, 256, 0, stream>>>(q_att, k_att, vt, y_att);
    k_finalize<<<16384, 256, 0, stream>>>(y_att, qkvg + 3 * M * HID, ow, yg);
    // output projection
    k_gemm<<<dim3(32, 16, 1), 256, 0, stream>>>(yg, Wt + (size_t)4 * 2048 * 2048, (float*)d_out,
                                                (int)M, 2048, 2048);
}

// Round 5
// 327.855 us; speedup vs baseline: 1.8333x; 1.0440x over previous
//
#include <hip/hip_runtime.h>
#include <hip/hip_bf16.h>
#include <stdint.h>

typedef __bf16 bf16x8 __attribute__((ext_vector_type(8)));
typedef float f32x4 __attribute__((ext_vector_type(4)));
typedef __hip_bfloat16 bf16;

__device__ __forceinline__ void gload16(const void* g, void* l) {
    __builtin_amdgcn_global_load_lds(
        (const __attribute__((address_space(1))) uint32_t*)g,
        (__attribute__((address_space(3))) uint32_t*)l,
        16, 0, 0);
}

// ---------------- elementwise convert fp32 -> bf16 (x) ----------------
__global__ void k_cvt_bf16(const float* __restrict__ in, bf16* __restrict__ out, int n4) {
    int i = blockIdx.x * blockDim.x + threadIdx.x;
    if (i >= n4) return;
    float4 v = reinterpret_cast<const float4*>(in)[i];
    union { bf16 h[4]; uint2 u; } pk;
    pk.h[0] = __float2bfloat16(v.x);
    pk.h[1] = __float2bfloat16(v.y);
    pk.h[2] = __float2bfloat16(v.z);
    pk.h[3] = __float2bfloat16(v.w);
    reinterpret_cast<uint2*>(out)[i] = pk.u;
}

// ---------------- rope cos/sin table [T][128] (cos j | sin j) ----------------
__global__ void k_rope_tbl(float* __restrict__ tbl) {
    int i = blockIdx.x * blockDim.x + threadIdx.x; // T*64
    int t = i >> 6, j = i & 63;
    float inv = powf(10000.0f, -(float)j * (1.0f / 64.0f));
    float f = (float)t * inv;
    tbl[t * 128 + j] = cosf(f);
    tbl[t * 128 + 64 + j] = sinf(f);
}

// ---------------- weight transpose + convert: W[k][n] fp32 -> Wt[n][k] bf16 ----------------
__global__ void k_wtrans(const float* __restrict__ w0, const float* __restrict__ w1,
                         const float* __restrict__ w2, const float* __restrict__ w3,
                         const float* __restrict__ w4, bf16* __restrict__ out) {
    __shared__ float tile[32][33];
    const float* srcs[5] = {w0, w1, w2, w3, w4};
    const float* src = srcs[blockIdx.z];
    bf16* dst = out + (size_t)blockIdx.z * 2048 * 2048;
    int k0 = blockIdx.x * 32, n0 = blockIdx.y * 32;
    int tx = threadIdx.x, ty = threadIdx.y; // 32 x 8
#pragma unroll
    for (int i = 0; i < 4; i++)
        tile[ty + 8 * i][tx] = src[(size_t)(k0 + ty + 8 * i) * 2048 + n0 + tx];
    __syncthreads();
#pragma unroll
    for (int i = 0; i < 4; i++)
        dst[(size_t)(n0 + ty + 8 * i) * 2048 + k0 + tx] = __float2bfloat16(tile[tx][ty + 8 * i]);
}

// ---------------- GEMM 128x128 (m97-structure), used for the output projection ----------------
__global__ __launch_bounds__(256) void k_gemm(
    const bf16* __restrict__ A, const bf16* __restrict__ Bt, float* __restrict__ C,
    int M, int N, int K) {
    __shared__ __align__(16) bf16 As[128 * 64];
    __shared__ __align__(16) bf16 Bs[128 * 64];
    int lane = threadIdx.x & 63, wave = threadIdx.x >> 6;
    int g = lane >> 4, cc = lane & 15;
    int wr = wave >> 1, wc = wave & 1;
    size_t m0 = (size_t)blockIdx.x * 128, n0 = (size_t)blockIdx.y * 128;
    const bf16* Ab = A + m0 * K;
    const bf16* Bb = Bt + (size_t)blockIdx.z * N * K + n0 * K;
    float* Cb = C + (size_t)blockIdx.z * M * N + m0 * N + n0;

    f32x4 acc[4][4];
#pragma unroll
    for (int i = 0; i < 4; i++)
#pragma unroll
        for (int j = 0; j < 4; j++) acc[i][j] = {0.f, 0.f, 0.f, 0.f};

    int scol = (lane & 7) * 8;
    for (int k0 = 0; k0 < K; k0 += 64) {
#pragma unroll
        for (int i = 0; i < 4; i++) {
            int ch = wave * 4 + i;
            int row = ch * 8 + (lane >> 3);
            gload16(&Ab[(size_t)row * K + k0 + scol], &As[ch * 512]);
            gload16(&Bb[(size_t)row * K + k0 + scol], &Bs[ch * 512]);
        }
        __syncthreads();
#pragma unroll
        for (int kk = 0; kk < 2; kk++) {
            bf16x8 af[4], bfr[4];
#pragma unroll
            for (int m = 0; m < 4; m++)
                af[m] = *reinterpret_cast<const bf16x8*>(&As[(wr * 64 + m * 16 + cc) * 64 + kk * 32 + g * 8]);
#pragma unroll
            for (int n = 0; n < 4; n++)
                bfr[n] = *reinterpret_cast<const bf16x8*>(&Bs[(wc * 64 + n * 16 + cc) * 64 + kk * 32 + g * 8]);
#pragma unroll
            for (int m = 0; m < 4; m++)
#pragma unroll
                for (int n = 0; n < 4; n++)
                    acc[m][n] = __builtin_amdgcn_mfma_f32_16x16x32_bf16(af[m], bfr[n], acc[m][n], 0, 0, 0);
        }
        __syncthreads();
    }
#pragma unroll
    for (int m = 0; m < 4; m++)
#pragma unroll
        for (int n = 0; n < 4; n++)
#pragma unroll
            for (int r = 0; r < 4; r++) {
                size_t row = wr * 64 + m * 16 + g * 4 + r;
                Cb[row * N + (wc * 64 + n * 16 + cc)] = acc[m][n][r];
            }
}

// ---------------- GEMM 256x256 v2: spread-read 4-phase schedule, bf16 out ----------------
// C[z][M][N] = A[M][K] @ Bt[z][N][K]^T (bf16 out). 512 thr = 8 waves (2M x 4N), BK=64.
// LDS 128KB: [2 buf][8 quarter][64 x 64] bf16, XOR-swizzled (unit ^= row&7).
// Quarters: 0..3 = A rows q*64.., 4..7 = Bt rows (q-4)*64.. Stage unit = 1 quarter
// (1 gload16/thread). Reads/phase: ph1 A-mh0(8)+B-nh0(4); ph2 B-nh1(4); ph3 A-mh1(8); ph4 0.
// Region deaths: Aq0,Aq2@ph1; Bq*@ph2; Aq1,Aq3@ph3. Stages: ph1->(t+1).Aq1,Aq3 [other buf];
// ph2->(t+2).Aq0,Aq2; ph3->(t+2).Bq0,Bq1; ph4->(t+2).Bq2,Bq3. vmcnt(6)@ph4 retires t+1's units.
__global__ __launch_bounds__(512, 2) void k_gemm256(
    const bf16* __restrict__ A, const bf16* __restrict__ Bt, bf16* __restrict__ C,
    int M, int N, int K) {
    __shared__ __align__(16) bf16 lds[2][8][64 * 64];
    const int tid = threadIdx.x;
    const int lane = tid & 63, wave = tid >> 6;
    const int g = lane >> 4, c = lane & 15, cx = c & 7;
    const int wr = wave >> 2, wc = wave & 3;  // 2M x 4N
    // bijective XCD swizzle (nwg=512, %8==0): chunk of 64 ids per XCD, x fastest
    const int id = blockIdx.x;
    const int swz = (id & 7) * 64 + (id >> 3);
    const int xt = swz & 15, yt = (swz >> 4) & 7, zt = swz >> 7;
    const size_t m0 = (size_t)xt * 256, n0 = (size_t)yt * 256;
    const bf16* Ab = A + m0 * K;
    const bf16* Bb = Bt + (size_t)zt * (size_t)N * K + n0 * K;
    bf16* Cb = C + (size_t)zt * (size_t)M * N + m0 * N + n0;
    const int nt = K >> 6;

    const int srow = tid >> 3;                      // 0..63
    const int scol = ((tid & 7) ^ (srow & 7)) * 8;  // inverse-swizzled source col

    auto stage = [&](int u, int q) {
        if (u >= nt) return;
        const bf16* src = (q < 4) ? &Ab[(size_t)(q * 64 + srow) * K]
                                  : &Bb[(size_t)((q - 4) * 64 + srow) * K];
        gload16(&src[((size_t)u << 6) + scol], &lds[u & 1][q][wave * 512]);
    };

    f32x4 acc[8][4];
#pragma unroll
    for (int i = 0; i < 8; i++)
#pragma unroll
        for (int j = 0; j < 4; j++) acc[i][j] = {0.f, 0.f, 0.f, 0.f};

    // prologue: tile0 all 8 quarters; tile1: Aq0,Aq2,Bq0..3 (Aq1,Aq3 staged at t0.ph1)
#pragma unroll
    for (int q = 0; q < 8; q++) stage(0, q);
    stage(1, 0); stage(1, 2); stage(1, 4); stage(1, 5); stage(1, 6); stage(1, 7);
    asm volatile("s_waitcnt vmcnt(6)" ::: "memory");
    __builtin_amdgcn_s_barrier();

    bf16x8 afr[4][2], bfr[2][2][2];

#define READ_A(mh)                                                                   \
    do {                                                                             \
        const bf16* aq = &lds[t & 1][wr * 2 + (mh)][0];                              \
        _Pragma("unroll") for (int m_ = 0; m_ < 4; m_++)                             \
            _Pragma("unroll") for (int kh = 0; kh < 2; kh++)                         \
                afr[m_][kh] = *reinterpret_cast<const bf16x8*>(                      \
                    aq + (m_ * 16 + c) * 64 + ((kh * 4 + g) ^ cx) * 8);              \
    } while (0)
#define READ_B(nh)                                                                   \
    do {                                                                             \
        const bf16* bq = &lds[t & 1][4 + wc][0];                                     \
        _Pragma("unroll") for (int n_ = 0; n_ < 2; n_++)                             \
            _Pragma("unroll") for (int kh = 0; kh < 2; kh++)                         \
                bfr[nh][n_][kh] = *reinterpret_cast<const bf16x8*>(                  \
                    bq + (((nh)*2 + n_) * 16 + c) * 64 + ((kh * 4 + g) ^ cx) * 8);   \
    } while (0)
#define QUAD(mh, nh)                                                                 \
    do {                                                                             \
        __builtin_amdgcn_s_setprio(1);                                               \
        _Pragma("unroll") for (int kh = 0; kh < 2; kh++)                             \
            _Pragma("unroll") for (int m_ = 0; m_ < 4; m_++)                         \
                _Pragma("unroll") for (int n_ = 0; n_ < 2; n_++)                     \
                    acc[(mh)*4 + m_][(nh)*2 + n_] =                                  \
                        __builtin_amdgcn_mfma_f32_16x16x32_bf16(                     \
                            afr[m_][kh], bfr[nh][n_][kh],                            \
                            acc[(mh)*4 + m_][(nh)*2 + n_], 0, 0, 0);                 \
        __builtin_amdgcn_s_setprio(0);                                               \
    } while (0)

    for (int t = 0; t < nt; ++t) {
        // ---- ph1 ----
        READ_A(0);
        READ_B(0);
        stage(t + 1, 1); stage(t + 1, 3);
        __builtin_amdgcn_s_barrier();
        asm volatile("s_waitcnt lgkmcnt(0)" ::: "memory");
        __builtin_amdgcn_sched_barrier(0);
        QUAD(0, 0);
        __builtin_amdgcn_s_barrier();
        // ---- ph2 ----
        READ_B(1);
        stage(t + 2, 0); stage(t + 2, 2);
        __builtin_amdgcn_s_barrier();
        asm volatile("s_waitcnt lgkmcnt(0)" ::: "memory");
        __builtin_amdgcn_sched_barrier(0);
        QUAD(0, 1);
        __builtin_amdgcn_s_barrier();
        // ---- ph3 ----
        READ_A(1);
        stage(t + 2, 4); stage(t + 2, 5);
        __builtin_amdgcn_s_barrier();
        asm volatile("s_waitcnt lgkmcnt(0)" ::: "memory");
        __builtin_amdgcn_sched_barrier(0);
        QUAD(1, 0);
        __builtin_amdgcn_s_barrier();
        // ---- ph4 ----
        stage(t + 2, 6); stage(t + 2, 7);
        if (t < nt - 2) asm volatile("s_waitcnt vmcnt(6)" ::: "memory");
        else            asm volatile("s_waitcnt vmcnt(0)" ::: "memory");
        __builtin_amdgcn_s_barrier();
        __builtin_amdgcn_sched_barrier(0);
        QUAD(1, 1);
        __builtin_amdgcn_s_barrier();
    }
#undef READ_A
#undef READ_B
#undef QUAD
    // epilogue: bf16 scalar stores (4x32B segments per instr)
#pragma unroll
    for (int m_ = 0; m_ < 8; m_++)
#pragma unroll
        for (int n_ = 0; n_ < 4; n_++)
#pragma unroll
            for (int r_ = 0; r_ < 4; r_++) {
                size_t row = wr * 128 + m_ * 16 + g * 4 + r_;
                Cb[row * N + wc * 64 + n_ * 16 + c] = __float2bfloat16(acc[m_][n_][r_]);
            }
}

// ---------------- RoPE + per-head RMS norm, bf16 [B*T][2048] -> bf16 [BH][T][128] ----------------
__global__ void k_rope_rms(const bf16* __restrict__ src, const float* __restrict__ rmsw,
                           const float* __restrict__ tbl, bf16* __restrict__ dst,
                           float outscale) {
    const int T = 2048;
    int wv = blockIdx.x * 4 + (threadIdx.x >> 6); // over B*T*H, h fastest
    int lane = threadIdx.x & 63;
    int h = wv & 15, bt = wv >> 4;
    int t = bt & (T - 1), b_ = bt >> 11;
    const bf16* p = src + (size_t)bt * 2048 + h * 128;
    float a = __bfloat162float(p[lane]), b = __bfloat162float(p[lane + 64]);
    float cs = tbl[t * 128 + lane], sn = tbl[t * 128 + 64 + lane];
    float r1 = a * cs - b * sn, r2 = a * sn + b * cs;
    float ss = r1 * r1 + r2 * r2;
#pragma unroll
    for (int d = 1; d < 64; d <<= 1) ss += __shfl_xor(ss, d, 64);
    float rs = rsqrtf(ss * (1.0f / 128.0f) + 1e-5f);
    size_t o = ((size_t)(b_ * 16 + h) * T + t) * 128;
    dst[o + lane] = __float2bfloat16(r1 * rs * rmsw[lane] * outscale);
    dst[o + lane + 64] = __float2bfloat16(r2 * rs * rmsw[lane + 64] * outscale);
}

// ---------------- V transpose: bf16 [B*T][2048] -> bf16 Vt [BH][128][T] ----------------
__global__ void k_vtrans(const bf16* __restrict__ V, bf16* __restrict__ Vt) {
    const int T = 2048;
    __shared__ float tile[32][33];
    int bh = blockIdx.z, b_ = bh >> 4, h = bh & 15;
    int t0 = blockIdx.x * 32, d0 = blockIdx.y * 32;
    int tx = threadIdx.x, ty = threadIdx.y; // 32 x 8
#pragma unroll
    for (int i = 0; i < 4; i++)
        tile[ty + 8 * i][tx] =
            __bfloat162float(V[((size_t)(b_ * T + t0 + ty + 8 * i)) * 2048 + h * 128 + d0 + tx]);
    __syncthreads();
#pragma unroll
    for (int i = 0; i < 4; i++)
        Vt[((size_t)bh * 128 + d0 + ty + 8 * i) * T + t0 + tx] = __float2bfloat16(tile[tx][ty + 8 * i]);
}

// ---------------- causal flash attention v3 ----------------
__global__ __launch_bounds__(256) void k_attn(
    const bf16* __restrict__ Q, const bf16* __restrict__ K,
    const bf16* __restrict__ Vt, float* __restrict__ Y) {
    const int T = 2048;
    __shared__ __align__(16) bf16 KsB[2][64 * 128];
    __shared__ __align__(16) bf16 VsB[2][128 * 64];
    __shared__ __align__(16) bf16 Ps[64 * 72];
    int lane = threadIdx.x & 63, wave = threadIdx.x >> 6;
    int g = lane >> 4, c = lane & 15;
    int wg = blockIdx.x;
    int bh = wg & 31;          // XCD = bh%8 -> 4 heads per XCD (K+V = 4MB = one L2)
    int qt = 31 - (wg >> 5);   // heavy q-tiles launch first
    int q0 = qt * 64;
    const bf16* Qb = Q + (size_t)bh * T * 128;
    const bf16* Kb = K + (size_t)bh * T * 128;
    const bf16* Vb = Vt + (size_t)bh * 128 * T;

    int qrow = q0 + wave * 16 + c;
    bf16x8 qf[4];
#pragma unroll
    for (int kk = 0; kk < 4; kk++)
        qf[kk] = *reinterpret_cast<const bf16x8*>(&Qb[(size_t)qrow * 128 + kk * 32 + g * 8]);

    int kli = lane >> 4;
    int vli = lane >> 3;
    int vlu = (lane & 7) ^ (vli & 7);

    auto stage = [&](int kv0, int b) {
#pragma unroll
        for (int i = 0; i < 4; i++) {
            int ch = wave * 4 + i;
            int krow = ch * 4 + kli;
            int klu = (lane & 15) ^ (krow & 7);
            gload16(&Kb[(size_t)(kv0 + krow) * 128 + klu * 8], &KsB[b][ch * 512]);
            int vrow = ch * 8 + vli;
            gload16(&Vb[(size_t)vrow * T + kv0 + vlu * 8], &VsB[b][ch * 512]);
        }
    };

    f32x4 acc[8];
#pragma unroll
    for (int i = 0; i < 8; i++) acc[i] = {0.f, 0.f, 0.f, 0.f};
    float m = -INFINITY, l = 0.f;

    int ntiles = qt + 1;
    stage(0, 0);
    __syncthreads();
    int cur = 0;
    for (int it = 0; it < ntiles; ++it) {
        int kv0 = it * 64;
        if (it + 1 < ntiles) stage(kv0 + 64, cur ^ 1);
        const bf16* Ks = KsB[cur];
        const bf16* Vs = VsB[cur];

        f32x4 s[4];
#pragma unroll
        for (int nf = 0; nf < 4; nf++) s[nf] = {0.f, 0.f, 0.f, 0.f};
#pragma unroll
        for (int nf = 0; nf < 4; nf++)
#pragma unroll
            for (int kk = 0; kk < 4; kk++) {
                int pu = (kk * 4 + g) ^ (c & 7);
                bf16x8 kf = *reinterpret_cast<const bf16x8*>(&Ks[(nf * 16 + c) * 128 + pu * 8]);
                s[nf] = __builtin_amdgcn_mfma_f32_16x16x32_bf16(kf, qf[kk], s[nf], 0, 0, 0);
            }
        if (it == ntiles - 1) {
#pragma unroll
            for (int nf = 0; nf < 4; nf++)
#pragma unroll
                for (int r = 0; r < 4; r++)
                    if (kv0 + nf * 16 + g * 4 + r > qrow) s[nf][r] = -1e30f;
        }
        float mx = -INFINITY;
#pragma unroll
        for (int nf = 0; nf < 4; nf++)
#pragma unroll
            for (int r = 0; r < 4; r++) mx = fmaxf(mx, s[nf][r]);
        mx = fmaxf(mx, __shfl_xor(mx, 16, 64));
        mx = fmaxf(mx, __shfl_xor(mx, 32, 64));
        float mnew = fmaxf(m, mx);
        float alpha = __expf(m - mnew);
        m = mnew;
        float rsum = 0.f;
#pragma unroll
        for (int nf = 0; nf < 4; nf++)
#pragma unroll
            for (int r = 0; r < 4; r++) {
                float p = __expf(s[nf][r] - mnew);
                s[nf][r] = p;
                rsum += p;
            }
        rsum += __shfl_xor(rsum, 16, 64);
        rsum += __shfl_xor(rsum, 32, 64);
        l = l * alpha + rsum;
        float al[4];
#pragma unroll
        for (int r = 0; r < 4; r++) al[r] = __shfl(alpha, g * 4 + r, 64);
#pragma unroll
        for (int nf = 0; nf < 8; nf++)
#pragma unroll
            for (int r = 0; r < 4; r++) acc[nf][r] *= al[r];
#pragma unroll
        for (int nf = 0; nf < 4; nf++) {
            union { bf16 h[4]; uint2 u; } pk;
#pragma unroll
            for (int r = 0; r < 4; r++) pk.h[r] = __float2bfloat16(s[nf][r]);
            *reinterpret_cast<uint2*>(&Ps[(wave * 16 + c) * 72 + nf * 16 + g * 4]) = pk.u;
        }
#pragma unroll
        for (int kk2 = 0; kk2 < 2; kk2++) {
            bf16x8 pf = *reinterpret_cast<const bf16x8*>(&Ps[(wave * 16 + c) * 72 + kk2 * 32 + g * 8]);
#pragma unroll
            for (int nf = 0; nf < 8; nf++) {
                int pu = (kk2 * 4 + g) ^ (c & 7);
                bf16x8 vf = *reinterpret_cast<const bf16x8*>(&Vs[(nf * 16 + c) * 64 + pu * 8]);
                acc[nf] = __builtin_amdgcn_mfma_f32_16x16x32_bf16(pf, vf, acc[nf], 0, 0, 0);
            }
        }
        __syncthreads();
        cur ^= 1;
    }
    float inv = 1.0f / l;
    float iv[4];
#pragma unroll
    for (int r = 0; r < 4; r++) iv[r] = __shfl(inv, g * 4 + r, 64);
#pragma unroll
    for (int r = 0; r < 4; r++) {
        size_t row = q0 + wave * 16 + g * 4 + r;
#pragma unroll
        for (int nf = 0; nf < 8; nf++)
            Y[(size_t)bh * T * 128 + row * 128 + nf * 16 + c] = acc[nf][r] * iv[r];
    }
}

// ---------------- o-norm + silu(gate) gating -> bf16 [B*T][2048] ----------------
__global__ void k_finalize(const float* __restrict__ Y, const bf16* __restrict__ gate,
                           const float* __restrict__ ow, bf16* __restrict__ out) {
    const int T = 2048;
    int wv = blockIdx.x * 4 + (threadIdx.x >> 6); // over BH*T
    int lane = threadIdx.x & 63;
    int t = wv & (T - 1), bh = wv >> 11;
    int b_ = bh >> 4, h = bh & 15;
    const float* y = Y + (size_t)wv * 128;
    float y1 = y[lane], y2 = y[lane + 64];
    float ss = y1 * y1 + y2 * y2;
#pragma unroll
    for (int d = 1; d < 64; d <<= 1) ss += __shfl_xor(ss, d, 64);
    float rs = rsqrtf(ss * (1.0f / 128.0f) + 1e-5f);
    size_t gi = ((size_t)(b_ * T + t)) * 2048 + h * 128;
    float g1 = __bfloat162float(gate[gi + lane]), g2 = __bfloat162float(gate[gi + lane + 64]);
    g1 = g1 / (1.f + __expf(-g1));
    g2 = g2 / (1.f + __expf(-g2));
    out[gi + lane] = __float2bfloat16(y1 * rs * ow[lane] * g1);
    out[gi + lane + 64] = __float2bfloat16(y2 * rs * ow[lane + 64] * g2);
}

extern "C" void kernel_launch(void* const* d_in, const int* in_sizes, int n_in,
                              void* d_out, int out_size, void* d_ws, size_t ws_size,
                              hipStream_t stream) {
    const float* x  = (const float*)d_in[0];
    const float* Wq = (const float*)d_in[1];
    const float* Wk = (const float*)d_in[2];
    const float* Wv = (const float*)d_in[3];
    const float* Wg = (const float*)d_in[4];
    const float* Wo = (const float*)d_in[5];
    const float* qw = (const float*)d_in[6];
    const float* kw = (const float*)d_in[7];
    const float* ow = (const float*)d_in[8];

    const size_t M = 4096, HID = 2048;
    char* w = (char*)d_ws;
    bf16*  xb    = (bf16*)(w);                     // @0          16,777,216 B
    bf16*  Wt    = (bf16*)(w + 16777216);          // @16M        41,943,040 B [5][2048][2048]
    bf16*  qkvg  = (bf16*)(w + 58720256);          // @56M        67,108,864 B [4][4096][2048] bf16
    bf16*  q_att = (bf16*)(w + 125829120);         //             16,777,216 B [32][2048][128]
    bf16*  k_att = (bf16*)(w + 142606336);         //             16,777,216 B
    bf16*  vt    = (bf16*)(w + 159383552);         //             16,777,216 B [32][128][2048]
    float* tbl   = (float*)(w + 176160768);        //              1,048,576 B [2048][128]
    float* y_att = (float*)(w + 177209344);        //             33,554,432 B [32][2048][128] fp32
    bf16*  yg    = (bf16*)(w + 210763776);         //             16,777,216 B [B*T][2048]

    k_cvt_bf16<<<8192, 256, 0, stream>>>(x, xb, (int)(M * HID / 4));
    k_rope_tbl<<<512, 256, 0, stream>>>(tbl);
    k_wtrans<<<dim3(64, 64, 5), dim3(32, 8), 0, stream>>>(Wq, Wk, Wv, Wg, Wo, Wt);
    // fused Q/K/V/Gate projection: 256x256 spread-read schedule, bf16 out, XCD-swizzled 1D grid
    k_gemm256<<<512, 512, 0, stream>>>(xb, Wt, qkvg, (int)M, 2048, 2048);
    // rope + rms (+ fold 1/sqrt(D) into q)
    k_rope_rms<<<16384, 256, 0, stream>>>(qkvg, qw, tbl, q_att, 0.08838834764831845f);
    k_rope_rms<<<16384, 256, 0, stream>>>(qkvg + M * HID, kw, tbl, k_att, 1.0f);
    k_vtrans<<<dim3(64, 4, 32), dim3(32, 8), 0, stream>>>(qkvg + 2 * M * HID, vt);
    k_attn<<<1024, 256, 0, stream>>>(q_att, k_att, vt, y_att);
    k_finalize<<<16384, 256, 0, stream>>>(y_att, qkvg + 3 * M * HID, ow, yg);
    // output projection (fp32 out to d_out)
    k_gemm<<<dim3(32, 16, 1), 256, 0, stream>>>(yg, Wt + (size_t)4 * 2048 * 2048, (float*)d_out,
                                                (int)M, 2048, 2048);
}